// Round 6
// baseline (641.398 us; speedup 1.0000x reference)
//
#include <hip/hip_runtime.h>

#define T_ 7
#define H_ 64
#define W_ 64
#define KK_ 27
#define HW_ 4096
#define THW_ 28672
#define CO_OFF 54

// ---------------------------------------------------------------------------
// Weight transpose: dst[k][c][o] = (o < Co) ? src[o*1728 + c*27 + k] : 0
// ---------------------------------------------------------------------------
__global__ void prep_wt_kernel(const float* __restrict__ w_off0,
                               const float* __restrict__ w_off1,
                               const float* __restrict__ w0,
                               const float* __restrict__ w1,
                               float* __restrict__ wcT0, float* __restrict__ wcT1,
                               float* __restrict__ wdT0, float* __restrict__ wdT1) {
    int idx = blockIdx.x * 256 + threadIdx.x;      // 4 * 110592 total
    int which = idx / 110592;
    int r = idx - which * 110592;
    int k = r >> 12;
    int c = (r >> 6) & 63;
    int o = r & 63;
    const float* src;
    float* dst;
    int Co;
    switch (which) {
        case 0:  src = w_off0; dst = wcT0; Co = CO_OFF; break;
        case 1:  src = w_off1; dst = wcT1; Co = CO_OFF; break;
        case 2:  src = w0;     dst = wdT0; Co = 64;     break;
        default: src = w1;     dst = wdT1; Co = 64;     break;
    }
    float v = 0.f;
    if (o < Co) v = src[o * 1728 + c * 27 + k];
    dst[r] = v;
}

// ---------------------------------------------------------------------------
// Plain 3x3x3 conv, split-K (512 thr), double-buffered LDS + async staging:
// issue next-tap loads into registers, GEMM current tap (hides latency),
// write next buffer after GEMM, one barrier per tap.
// ---------------------------------------------------------------------------
__global__ void __launch_bounds__(512, 4) conv_off_kernel(
    const float* __restrict__ in, const float* __restrict__ wT,
    const float* __restrict__ bias, float* __restrict__ out) {
    __shared__ __align__(16) float la[2][64][64];    // 32 KB
    __shared__ __align__(16) float lwt[2][64][64];   // 32 KB
    const int tid = threadIdx.x;
    const int bid = blockIdx.x;
    const int t = bid >> 6, h = bid & 63;
    const int w = tid & 63, cg = tid >> 6;
    const int grp = tid >> 8;
    const int l = tid & 255;
    const int obase = (l >> 4) * 4, wbase = (l & 15) * 4;
    const int cbase = grp * 32;

    float acc[4][4] = {};
    float rv[8];
    float4 wv0, wv1;
    const float4* s4 = reinterpret_cast<const float4*>(wT) + tid;  // +1024/tap

    // ---- prologue: stage tap 0 into buffer 0 ----
    {
        const int ts = t - 1, hs = h - 1, wsr = w - 1;
        const bool ok = ((unsigned)ts < 7u) & ((unsigned)hs < 64u) & ((unsigned)wsr < 64u);
        const float* src = in + (ts * HW_ + hs * W_ + wsr) + (cg * 8) * THW_;
#pragma unroll
        for (int i = 0; i < 8; ++i) { rv[i] = ok ? src[0] : 0.f; src += THW_; }
        wv0 = s4[0]; wv1 = s4[512]; s4 += 1024;
#pragma unroll
        for (int i = 0; i < 8; ++i) la[0][cg * 8 + i][w] = rv[i];
        float4* l4 = reinterpret_cast<float4*>(&lwt[0][0][0]);
        l4[tid] = wv0; l4[tid + 512] = wv1;
    }
    __syncthreads();

    for (int k = 0; k < KK_; ++k) {
        const int cur = k & 1, nxt = cur ^ 1;
        // ---- issue next-tap loads (latency hides under GEMM) ----
        if (k + 1 < KK_) {
            const int kk = k + 1;
            const int kt = kk / 9 - 1, kh = (kk / 3) % 3 - 1, kw = kk % 3 - 1;
            const int ts = t + kt, hs = h + kh, wsr = w + kw;
            const bool ok = ((unsigned)ts < 7u) & ((unsigned)hs < 64u) & ((unsigned)wsr < 64u);
            const float* src = in + (ts * HW_ + hs * W_ + wsr) + (cg * 8) * THW_;
#pragma unroll
            for (int i = 0; i < 8; ++i) { rv[i] = ok ? src[0] : 0.f; src += THW_; }
            wv0 = s4[0]; wv1 = s4[512]; s4 += 1024;
        }
        // ---- GEMM on current buffer ----
#pragma unroll 8
        for (int c = 0; c < 32; ++c) {
            const float4 av = *reinterpret_cast<const float4*>(&la[cur][cbase + c][wbase]);
            const float4 wvv = *reinterpret_cast<const float4*>(&lwt[cur][cbase + c][obase]);
            const float a4[4] = {av.x, av.y, av.z, av.w};
            const float w4[4] = {wvv.x, wvv.y, wvv.z, wvv.w};
#pragma unroll
            for (int io = 0; io < 4; ++io)
#pragma unroll
                for (int iw = 0; iw < 4; ++iw)
                    acc[io][iw] = fmaf(w4[io], a4[iw], acc[io][iw]);
        }
        // ---- write next buffer ----
        if (k + 1 < KK_) {
#pragma unroll
            for (int i = 0; i < 8; ++i) la[nxt][cg * 8 + i][w] = rv[i];
            float4* l4 = reinterpret_cast<float4*>(&lwt[nxt][0][0]);
            l4[tid] = wv0; l4[tid + 512] = wv1;
        }
        __syncthreads();
    }

    // split-K reduction: group 1 writes partials, group 0 adds + stores
    float4* red = reinterpret_cast<float4*>(&la[0][0][0]);
    if (grp == 1) {
#pragma unroll
        for (int io = 0; io < 4; ++io)
            red[l * 4 + io] = make_float4(acc[io][0], acc[io][1], acc[io][2], acc[io][3]);
    }
    __syncthreads();
    if (grp == 0) {
        const int sb = t * HW_ + h * W_ + wbase;
#pragma unroll
        for (int io = 0; io < 4; ++io) {
            const float4 r = red[l * 4 + io];
            acc[io][0] += r.x; acc[io][1] += r.y; acc[io][2] += r.z; acc[io][3] += r.w;
            const int o = obase + io;
            if (o < CO_OFF) {
                const float b = bias[o];
                float* dst = out + o * THW_ + sb;
#pragma unroll
                for (int iw = 0; iw < 4; ++iw) dst[iw] = acc[io][iw] + b;
            }
        }
    }
}

// ---------------------------------------------------------------------------
// Deformable conv, split-K 512-thread, double-buffered + async staging.
// Per tap: corners in registers; issue 32 raw corner loads + weights early;
// GEMM previous tap under the load latency; combine+write after GEMM.
// MODE 0: store leaky_relu(y).  MODE 1: store y + resid.
// ---------------------------------------------------------------------------
template <int MODE>
__global__ void __launch_bounds__(512, 4) dcn_kernel(
    const float* __restrict__ in, const float* __restrict__ off,
    const float* __restrict__ wT, const float* __restrict__ resid,
    float* __restrict__ out) {
    __shared__ __align__(16) float la[2][64][64];    // 32 KB
    __shared__ __align__(16) float lwt[2][64][64];   // 32 KB
    const int tid = threadIdx.x;
    const int bid = blockIdx.x;
    const int t = bid >> 6, h = bid & 63;
    const int w = tid & 63, cg = tid >> 6;
    const int grp = tid >> 8;
    const int l = tid & 255;
    const int obase = (l >> 4) * 4, wbase = (l & 15) * 4;
    const int cbase = grp * 32;

    float acc[4][4] = {};
    float rv[8][4];
    float g0, g1, g2, g3;
    float4 wv0, wv1;

    const int sidx = t * HW_ + h * W_ + w;
    const float* offp = off + sidx;                                // +2*THW_/tap
    const float4* s4 = reinterpret_cast<const float4*>(wT) + tid;  // +1024/tap
    const float* xbase = in + (cg * 8) * THW_;

    // ---- prologue: tap 0 offsets, gather, write buffer 0 ----
    float oh = offp[0], ow = offp[THW_];
    offp += 2 * THW_;
    {
        const int ts = t - 1;
        const bool tok = (unsigned)ts < 7u;
        const int tcb = ts < 0 ? 0 : ts;
        const float ph = (float)(h - 1) + oh;
        const float pw = (float)(w - 1) + ow;
        const float h0f = floorf(ph), w0f = floorf(pw);
        const float fh = ph - h0f, fw = pw - w0f;
        const int h0 = (int)h0f, w0i = (int)w0f;
        const int h1 = h0 + 1, w1i = w0i + 1;
        const bool h0k = (unsigned)h0 < 64u, h1k = (unsigned)h1 < 64u;
        const bool w0k = (unsigned)w0i < 64u, w1k = (unsigned)w1i < 64u;
        const int tb = tcb * HW_;
        const int h0c = (h0 < 0 ? 0 : (h0 > 63 ? 63 : h0)) * W_;
        const int h1c = (h1 < 0 ? 0 : (h1 > 63 ? 63 : h1)) * W_;
        const int w0c = w0i < 0 ? 0 : (w0i > 63 ? 63 : w0i);
        const int w1c = w1i < 0 ? 0 : (w1i > 63 ? 63 : w1i);
        const int i0 = tb + h0c + w0c, i1 = tb + h0c + w1c;
        const int i2 = tb + h1c + w0c, i3 = tb + h1c + w1c;
        g0 = (tok && h0k && w0k) ? (1.f - fh) * (1.f - fw) : 0.f;
        g1 = (tok && h0k && w1k) ? (1.f - fh) * fw : 0.f;
        g2 = (tok && h1k && w0k) ? fh * (1.f - fw) : 0.f;
        g3 = (tok && h1k && w1k) ? fh * fw : 0.f;
        const float* xc = xbase;
#pragma unroll
        for (int i = 0; i < 8; ++i) {
            rv[i][0] = xc[i0]; rv[i][1] = xc[i1]; rv[i][2] = xc[i2]; rv[i][3] = xc[i3];
            xc += THW_;
        }
        wv0 = s4[0]; wv1 = s4[512]; s4 += 1024;
#pragma unroll
        for (int i = 0; i < 8; ++i)
            la[0][cg * 8 + i][w] = g0 * rv[i][0] + g1 * rv[i][1] + g2 * rv[i][2] + g3 * rv[i][3];
        float4* l4 = reinterpret_cast<float4*>(&lwt[0][0][0]);
        l4[tid] = wv0; l4[tid + 512] = wv1;
    }
    // prefetch tap-1 offsets
    oh = offp[0]; ow = offp[THW_]; offp += 2 * THW_;
    __syncthreads();

    for (int k = 0; k < KK_; ++k) {
        const int cur = k & 1, nxt = cur ^ 1;
        if (k + 1 < KK_) {
            const int kk = k + 1;
            const int kt = kk / 9 - 1, kh = (kk / 3) % 3 - 1, kw = kk % 3 - 1;
            const int ts = t + kt;
            const bool tok = (unsigned)ts < 7u;
            const int tcb = ts < 0 ? 0 : (ts > 6 ? 6 : ts);
            const float ph = (float)(h + kh) + oh;
            const float pw = (float)(w + kw) + ow;
            const float h0f = floorf(ph), w0f = floorf(pw);
            const float fh = ph - h0f, fw = pw - w0f;
            const int h0 = (int)h0f, w0i = (int)w0f;
            const int h1 = h0 + 1, w1i = w0i + 1;
            const bool h0k = (unsigned)h0 < 64u, h1k = (unsigned)h1 < 64u;
            const bool w0k = (unsigned)w0i < 64u, w1k = (unsigned)w1i < 64u;
            const int tb = tcb * HW_;
            const int h0c = (h0 < 0 ? 0 : (h0 > 63 ? 63 : h0)) * W_;
            const int h1c = (h1 < 0 ? 0 : (h1 > 63 ? 63 : h1)) * W_;
            const int w0c = w0i < 0 ? 0 : (w0i > 63 ? 63 : w0i);
            const int w1c = w1i < 0 ? 0 : (w1i > 63 ? 63 : w1i);
            const int i0 = tb + h0c + w0c, i1 = tb + h0c + w1c;
            const int i2 = tb + h1c + w0c, i3 = tb + h1c + w1c;
            g0 = (tok && h0k && w0k) ? (1.f - fh) * (1.f - fw) : 0.f;
            g1 = (tok && h0k && w1k) ? (1.f - fh) * fw : 0.f;
            g2 = (tok && h1k && w0k) ? fh * (1.f - fw) : 0.f;
            g3 = (tok && h1k && w1k) ? fh * fw : 0.f;
            // issue raw corner loads (consumed after GEMM)
            const float* xc = xbase;
#pragma unroll
            for (int i = 0; i < 8; ++i) {
                rv[i][0] = xc[i0]; rv[i][1] = xc[i1]; rv[i][2] = xc[i2]; rv[i][3] = xc[i3];
                xc += THW_;
            }
            wv0 = s4[0]; wv1 = s4[512]; s4 += 1024;
            // prefetch offsets two taps ahead
            if (k + 2 < KK_) { oh = offp[0]; ow = offp[THW_]; offp += 2 * THW_; }
        }
        // ---- GEMM on current buffer (hides load latency) ----
#pragma unroll 8
        for (int c = 0; c < 32; ++c) {
            const float4 av = *reinterpret_cast<const float4*>(&la[cur][cbase + c][wbase]);
            const float4 wvv = *reinterpret_cast<const float4*>(&lwt[cur][cbase + c][obase]);
            const float a4[4] = {av.x, av.y, av.z, av.w};
            const float w4[4] = {wvv.x, wvv.y, wvv.z, wvv.w};
#pragma unroll
            for (int io = 0; io < 4; ++io)
#pragma unroll
                for (int iw = 0; iw < 4; ++iw)
                    acc[io][iw] = fmaf(w4[io], a4[iw], acc[io][iw]);
        }
        // ---- combine + write next buffer ----
        if (k + 1 < KK_) {
#pragma unroll
            for (int i = 0; i < 8; ++i)
                la[nxt][cg * 8 + i][w] = g0 * rv[i][0] + g1 * rv[i][1] + g2 * rv[i][2] + g3 * rv[i][3];
            float4* l4 = reinterpret_cast<float4*>(&lwt[nxt][0][0]);
            l4[tid] = wv0; l4[tid + 512] = wv1;
        }
        __syncthreads();
    }

    // split-K reduction: group 1 writes partials, group 0 adds + stores
    float4* red = reinterpret_cast<float4*>(&la[0][0][0]);
    if (grp == 1) {
#pragma unroll
        for (int io = 0; io < 4; ++io)
            red[l * 4 + io] = make_float4(acc[io][0], acc[io][1], acc[io][2], acc[io][3]);
    }
    __syncthreads();
    if (grp == 0) {
        const int sb = t * HW_ + h * W_ + wbase;
#pragma unroll
        for (int io = 0; io < 4; ++io) {
            const float4 r = red[l * 4 + io];
            acc[io][0] += r.x; acc[io][1] += r.y; acc[io][2] += r.z; acc[io][3] += r.w;
            const int o = obase + io;
            float* dst = out + o * THW_ + sb;
            if (MODE == 0) {
#pragma unroll
                for (int iw = 0; iw < 4; ++iw) {
                    const float v = acc[io][iw];
                    dst[iw] = v > 0.f ? v : 0.1f * v;
                }
            } else {
                const float* r2 = resid + o * THW_ + sb;
#pragma unroll
                for (int iw = 0; iw < 4; ++iw) dst[iw] = acc[io][iw] + r2[iw];
            }
        }
    }
}

// ---------------------------------------------------------------------------
extern "C" void kernel_launch(void* const* d_in, const int* in_sizes, int n_in,
                              void* d_out, int out_size, void* d_ws, size_t ws_size,
                              hipStream_t stream) {
    (void)in_sizes; (void)n_in; (void)out_size; (void)ws_size;
    const float* x      = (const float*)d_in[0];
    const float* w_off0 = (const float*)d_in[1];
    const float* b_off0 = (const float*)d_in[2];
    const float* w0     = (const float*)d_in[3];
    const float* w_off1 = (const float*)d_in[4];
    const float* b_off1 = (const float*)d_in[5];
    const float* w1     = (const float*)d_in[6];
    float* out = (float*)d_out;

    float* ws = (float*)d_ws;
    float* off_buf = ws;                        // 54 * 28672
    float* y_buf   = off_buf + CO_OFF * THW_;   // 64 * 28672
    float* wcT0 = y_buf + 64 * THW_;            // 27*64*64 each
    float* wcT1 = wcT0 + 27 * 4096;
    float* wdT0 = wcT1 + 27 * 4096;
    float* wdT1 = wdT0 + 27 * 4096;

    prep_wt_kernel<<<1728, 256, 0, stream>>>(w_off0, w_off1, w0, w1,
                                             wcT0, wcT1, wdT0, wdT1);
    conv_off_kernel<<<448, 512, 0, stream>>>(x, wcT0, b_off0, off_buf);
    dcn_kernel<0><<<448, 512, 0, stream>>>(x, off_buf, wdT0, nullptr, y_buf);
    conv_off_kernel<<<448, 512, 0, stream>>>(y_buf, wcT1, b_off1, off_buf);
    dcn_kernel<1><<<448, 512, 0, stream>>>(y_buf, off_buf, wdT1, x, out);
}

// Round 8
// 640.180 us; speedup vs baseline: 1.0019x; 1.0019x over previous
//
#include <hip/hip_runtime.h>

#define T_ 7
#define H_ 64
#define W_ 64
#define KK_ 27
#define HW_ 4096
#define THW_ 28672
#define CO_OFF 54

// ---------------------------------------------------------------------------
// Weight transpose: dst[k][c][o] = (o < Co) ? src[o*1728 + c*27 + k] : 0
// ---------------------------------------------------------------------------
__global__ void prep_wt_kernel(const float* __restrict__ w_off0,
                               const float* __restrict__ w_off1,
                               const float* __restrict__ w0,
                               const float* __restrict__ w1,
                               float* __restrict__ wcT0, float* __restrict__ wcT1,
                               float* __restrict__ wdT0, float* __restrict__ wdT1) {
    int idx = blockIdx.x * 256 + threadIdx.x;      // 4 * 110592 total
    int which = idx / 110592;
    int r = idx - which * 110592;
    int k = r >> 12;
    int c = (r >> 6) & 63;
    int o = r & 63;
    const float* src;
    float* dst;
    int Co;
    switch (which) {
        case 0:  src = w_off0; dst = wcT0; Co = CO_OFF; break;
        case 1:  src = w_off1; dst = wcT1; Co = CO_OFF; break;
        case 2:  src = w0;     dst = wdT0; Co = 64;     break;
        default: src = w1;     dst = wdT1; Co = 64;     break;
    }
    float v = 0.f;
    if (o < Co) v = src[o * 1728 + c * 27 + k];
    dst[r] = v;
}

// ---------------------------------------------------------------------------
// NCTHW -> NHWC-style transpose: xT[pos*64 + c] = x[c*THW + pos]
// One block per (t,h) row: 64 pos x 64 c tile via LDS.
// ---------------------------------------------------------------------------
__global__ void __launch_bounds__(256) transpose_kernel(
    const float* __restrict__ x, float* __restrict__ xT) {
    __shared__ float lx[64][65];
    const int tid = threadIdx.x;
    const int base = blockIdx.x * 64;      // t*4096 + h*64
    const int w = tid & 63, cg = tid >> 6; // cg 0..3
#pragma unroll
    for (int i = 0; i < 16; ++i) {
        const int c = cg * 16 + i;
        lx[c][w] = x[c * THW_ + base + w];
    }
    __syncthreads();
    const int c = tid & 63, j0 = tid >> 6;
#pragma unroll
    for (int j = 0; j < 16; ++j) {
        const int wp = j * 4 + j0;
        xT[(base + wp) * 64 + c] = lx[c][wp];
    }
}

// ---------------------------------------------------------------------------
// Plain 3x3x3 conv on NHWC input. Block = (t, h, w-half): 64 o x 32 w.
// 512 thr: staging thread (c4 0..15, wl 0..31) loads one float4 (4 channels,
// NHWC-contiguous) per tap; GEMM thread (grp, obase 0..60, wbase 0..30)
// computes 4o x 2w over K=32 (split-K in-block, LDS-reduced at end).
// ---------------------------------------------------------------------------
__global__ void __launch_bounds__(512, 8) conv_off_kernel(
    const float* __restrict__ xT, const float* __restrict__ wT,
    const float* __restrict__ bias, float* __restrict__ out) {
    __shared__ float la[64][34];                  // 8.5 KB (pad 34: b64-friendly)
    __shared__ __align__(16) float lwt[64][64];   // 16 KB
    const int tid = threadIdx.x;
    const int bid = blockIdx.x;
    const int t = bid >> 7, h = (bid >> 1) & 63, wh = bid & 1;
    const int wg = wh * 32;
    const int wl = tid & 31;
    const int c4 = (tid >> 5) & 15;
    const int w = wg + wl;
    const int grp = tid >> 8;
    const int l = tid & 255;
    const int obase = (l >> 4) * 4;
    const int wbase = (l & 15) * 2;
    const int cbase = grp * 32;

    float acc[4][2] = {};
    const float4* s4 = reinterpret_cast<const float4*>(wT) + tid;  // +1024/tap

    for (int k = 0; k < KK_; ++k) {
        const int kt = k / 9 - 1, kh = (k / 3) % 3 - 1, kw = k % 3 - 1;
        const int ts = t + kt, hs = h + kh, wsr = w + kw;
        const bool ok = ((unsigned)ts < 7u) & ((unsigned)hs < 64u) & ((unsigned)wsr < 64u);
        float4 v = make_float4(0.f, 0.f, 0.f, 0.f);
        if (ok)
            v = *reinterpret_cast<const float4*>(xT + (ts * HW_ + hs * W_ + wsr) * 64 + c4 * 4);
        la[c4 * 4 + 0][wl] = v.x;
        la[c4 * 4 + 1][wl] = v.y;
        la[c4 * 4 + 2][wl] = v.z;
        la[c4 * 4 + 3][wl] = v.w;
        float4* l4 = reinterpret_cast<float4*>(&lwt[0][0]);
        l4[tid] = s4[0];
        l4[tid + 512] = s4[512];
        s4 += 1024;
        __syncthreads();

#pragma unroll 8
        for (int c = 0; c < 32; ++c) {
            const float2 av = *reinterpret_cast<const float2*>(&la[cbase + c][wbase]);
            const float4 wv = *reinterpret_cast<const float4*>(&lwt[cbase + c][obase]);
            acc[0][0] = fmaf(wv.x, av.x, acc[0][0]);
            acc[0][1] = fmaf(wv.x, av.y, acc[0][1]);
            acc[1][0] = fmaf(wv.y, av.x, acc[1][0]);
            acc[1][1] = fmaf(wv.y, av.y, acc[1][1]);
            acc[2][0] = fmaf(wv.z, av.x, acc[2][0]);
            acc[2][1] = fmaf(wv.z, av.y, acc[2][1]);
            acc[3][0] = fmaf(wv.w, av.x, acc[3][0]);
            acc[3][1] = fmaf(wv.w, av.y, acc[3][1]);
        }
        __syncthreads();
    }

    // split-K reduction (grp1 partials via lwt), then epilogue
    float4* red = reinterpret_cast<float4*>(&lwt[0][0]);
    if (grp == 1) {
        red[l * 2 + 0] = make_float4(acc[0][0], acc[1][0], acc[2][0], acc[3][0]);
        red[l * 2 + 1] = make_float4(acc[0][1], acc[1][1], acc[2][1], acc[3][1]);
    }
    __syncthreads();
    if (grp == 0) {
        const float4 r0 = red[l * 2 + 0];
        const float4 r1 = red[l * 2 + 1];
        acc[0][0] += r0.x; acc[1][0] += r0.y; acc[2][0] += r0.z; acc[3][0] += r0.w;
        acc[0][1] += r1.x; acc[1][1] += r1.y; acc[2][1] += r1.z; acc[3][1] += r1.w;
        const int sb = t * HW_ + h * W_ + wg + wbase;
#pragma unroll
        for (int io = 0; io < 4; ++io) {
            const int o = obase + io;
            if (o < CO_OFF) {
                const float b = bias[o];
                out[o * THW_ + sb + 0] = acc[io][0] + b;
                out[o * THW_ + sb + 1] = acc[io][1] + b;
            }
        }
    }
}

// ---------------------------------------------------------------------------
// Deformable conv on NHWC input. Same block/tile shape as conv_off.
// Staging thread: per tap compute its w's bilinear corners (bounds folded
// into zero weights, clamped indices), gather 4 channels x 4 corners as
// 4 float4 loads, combine, write la. GEMM + split-K as conv.
// MODE 0: write leaky_relu(y) in NHWC (yT). MODE 1: write y + resid in NCTHW.
// ---------------------------------------------------------------------------
template <int MODE>
__global__ void __launch_bounds__(512, 8) dcn_kernel(
    const float* __restrict__ xT, const float* __restrict__ off,
    const float* __restrict__ wT, const float* __restrict__ resid,
    float* __restrict__ out) {
    __shared__ float la[64][34];
    __shared__ __align__(16) float lwt[64][64];
    const int tid = threadIdx.x;
    const int bid = blockIdx.x;
    const int t = bid >> 7, h = (bid >> 1) & 63, wh = bid & 1;
    const int wg = wh * 32;
    const int wl = tid & 31;
    const int c4 = (tid >> 5) & 15;
    const int w = wg + wl;
    const int grp = tid >> 8;
    const int l = tid & 255;
    const int obase = (l >> 4) * 4;
    const int wbase = (l & 15) * 2;
    const int cbase = grp * 32;

    float acc[4][2] = {};
    const int sidx = t * HW_ + h * W_ + w;
    const float* offp = off + sidx;                                // +2*THW_/tap
    const float4* s4 = reinterpret_cast<const float4*>(wT) + tid;  // +1024/tap

    for (int k = 0; k < KK_; ++k) {
        const int kt = k / 9 - 1, kh = (k / 3) % 3 - 1, kw = k % 3 - 1;
        const int ts = t + kt;
        const bool tok = (unsigned)ts < 7u;
        const int tcb = ts < 0 ? 0 : (ts > 6 ? 6 : ts);
        const float oh = offp[0];
        const float ow = offp[THW_];
        offp += 2 * THW_;
        const float ph = (float)(h + kh) + oh;
        const float pw = (float)(w + kw) + ow;
        const float h0f = floorf(ph), w0f = floorf(pw);
        const float fh = ph - h0f, fw = pw - w0f;
        const int h0 = (int)h0f, w0i = (int)w0f;
        const int h1 = h0 + 1, w1i = w0i + 1;
        const bool h0k = (unsigned)h0 < 64u, h1k = (unsigned)h1 < 64u;
        const bool w0k = (unsigned)w0i < 64u, w1k = (unsigned)w1i < 64u;
        const int tb = tcb * HW_;
        const int h0c = (h0 < 0 ? 0 : (h0 > 63 ? 63 : h0)) * W_;
        const int h1c = (h1 < 0 ? 0 : (h1 > 63 ? 63 : h1)) * W_;
        const int w0c = w0i < 0 ? 0 : (w0i > 63 ? 63 : w0i);
        const int w1c = w1i < 0 ? 0 : (w1i > 63 ? 63 : w1i);
        const float f0 = (tok && h0k && w0k) ? (1.f - fh) * (1.f - fw) : 0.f;
        const float f1 = (tok && h0k && w1k) ? (1.f - fh) * fw : 0.f;
        const float f2 = (tok && h1k && w0k) ? fh * (1.f - fw) : 0.f;
        const float f3 = (tok && h1k && w1k) ? fh * fw : 0.f;
        const int cb = c4 * 4;
        const float4 A = *reinterpret_cast<const float4*>(xT + (tb + h0c + w0c) * 64 + cb);
        const float4 B = *reinterpret_cast<const float4*>(xT + (tb + h0c + w1c) * 64 + cb);
        const float4 C = *reinterpret_cast<const float4*>(xT + (tb + h1c + w0c) * 64 + cb);
        const float4 D = *reinterpret_cast<const float4*>(xT + (tb + h1c + w1c) * 64 + cb);
        la[cb + 0][wl] = fmaf(f0, A.x, fmaf(f1, B.x, fmaf(f2, C.x, f3 * D.x)));
        la[cb + 1][wl] = fmaf(f0, A.y, fmaf(f1, B.y, fmaf(f2, C.y, f3 * D.y)));
        la[cb + 2][wl] = fmaf(f0, A.z, fmaf(f1, B.z, fmaf(f2, C.z, f3 * D.z)));
        la[cb + 3][wl] = fmaf(f0, A.w, fmaf(f1, B.w, fmaf(f2, C.w, f3 * D.w)));
        float4* l4 = reinterpret_cast<float4*>(&lwt[0][0]);
        l4[tid] = s4[0];
        l4[tid + 512] = s4[512];
        s4 += 1024;
        __syncthreads();

#pragma unroll 8
        for (int c = 0; c < 32; ++c) {
            const float2 av = *reinterpret_cast<const float2*>(&la[cbase + c][wbase]);
            const float4 wv = *reinterpret_cast<const float4*>(&lwt[cbase + c][obase]);
            acc[0][0] = fmaf(wv.x, av.x, acc[0][0]);
            acc[0][1] = fmaf(wv.x, av.y, acc[0][1]);
            acc[1][0] = fmaf(wv.y, av.x, acc[1][0]);
            acc[1][1] = fmaf(wv.y, av.y, acc[1][1]);
            acc[2][0] = fmaf(wv.z, av.x, acc[2][0]);
            acc[2][1] = fmaf(wv.z, av.y, acc[2][1]);
            acc[3][0] = fmaf(wv.w, av.x, acc[3][0]);
            acc[3][1] = fmaf(wv.w, av.y, acc[3][1]);
        }
        __syncthreads();
    }

    // split-K reduction
    float4* red = reinterpret_cast<float4*>(&lwt[0][0]);
    if (grp == 1) {
        red[l * 2 + 0] = make_float4(acc[0][0], acc[1][0], acc[2][0], acc[3][0]);
        red[l * 2 + 1] = make_float4(acc[0][1], acc[1][1], acc[2][1], acc[3][1]);
    }
    __syncthreads();
    if (grp == 0) {
        const float4 r0 = red[l * 2 + 0];
        const float4 r1 = red[l * 2 + 1];
        acc[0][0] += r0.x; acc[1][0] += r0.y; acc[2][0] += r0.z; acc[3][0] += r0.w;
        acc[0][1] += r1.x; acc[1][1] += r1.y; acc[2][1] += r1.z; acc[3][1] += r1.w;
        const int posb = t * HW_ + h * W_ + wg + wbase;
        if (MODE == 0) {
            // NHWC output with leaky-relu
#pragma unroll
            for (int iw = 0; iw < 2; ++iw) {
                float v0 = acc[0][iw], v1 = acc[1][iw], v2 = acc[2][iw], v3 = acc[3][iw];
                v0 = v0 > 0.f ? v0 : 0.1f * v0;
                v1 = v1 > 0.f ? v1 : 0.1f * v1;
                v2 = v2 > 0.f ? v2 : 0.1f * v2;
                v3 = v3 > 0.f ? v3 : 0.1f * v3;
                *reinterpret_cast<float4*>(out + (posb + iw) * 64 + obase) =
                    make_float4(v0, v1, v2, v3);
            }
        } else {
            // NCTHW output + residual
#pragma unroll
            for (int io = 0; io < 4; ++io) {
                const int o = obase + io;
                const float* r2 = resid + o * THW_ + posb;
                float* dst = out + o * THW_ + posb;
                dst[0] = acc[io][0] + r2[0];
                dst[1] = acc[io][1] + r2[1];
            }
        }
    }
}

// ---------------------------------------------------------------------------
extern "C" void kernel_launch(void* const* d_in, const int* in_sizes, int n_in,
                              void* d_out, int out_size, void* d_ws, size_t ws_size,
                              hipStream_t stream) {
    (void)in_sizes; (void)n_in; (void)out_size; (void)ws_size;
    const float* x      = (const float*)d_in[0];
    const float* w_off0 = (const float*)d_in[1];
    const float* b_off0 = (const float*)d_in[2];
    const float* w0     = (const float*)d_in[3];
    const float* w_off1 = (const float*)d_in[4];
    const float* b_off1 = (const float*)d_in[5];
    const float* w1     = (const float*)d_in[6];
    float* out = (float*)d_out;

    float* ws = (float*)d_ws;
    float* xT      = ws;                       // 64*28672 (NHWC x)
    float* yT      = xT + 64 * THW_;           // 64*28672 (NHWC y)
    float* off_buf = yT + 64 * THW_;           // 54*28672
    float* wcT0 = off_buf + CO_OFF * THW_;     // 27*64*64 each
    float* wcT1 = wcT0 + 27 * 4096;
    float* wdT0 = wcT1 + 27 * 4096;
    float* wdT1 = wdT0 + 27 * 4096;

    prep_wt_kernel<<<1728, 256, 0, stream>>>(w_off0, w_off1, w0, w1,
                                             wcT0, wcT1, wdT0, wdT1);
    transpose_kernel<<<448, 256, 0, stream>>>(x, xT);
    conv_off_kernel<<<896, 512, 0, stream>>>(xT, wcT0, b_off0, off_buf);
    dcn_kernel<0><<<896, 512, 0, stream>>>(xT, off_buf, wdT0, nullptr, yT);
    conv_off_kernel<<<896, 512, 0, stream>>>(yT, wcT1, b_off1, off_buf);
    dcn_kernel<1><<<896, 512, 0, stream>>>(yT, off_buf, wdT1, x, out);
}

// Round 9
// 631.258 us; speedup vs baseline: 1.0161x; 1.0141x over previous
//
#include <hip/hip_runtime.h>

#define T_ 7
#define H_ 64
#define W_ 64
#define KK_ 27
#define HW_ 4096
#define THW_ 28672
#define CO_OFF 54

// ---------------------------------------------------------------------------
// Weight transpose: dst[k][c][o] = (o < Co) ? src[o*1728 + c*27 + k] : 0
// ---------------------------------------------------------------------------
__global__ void prep_wt_kernel(const float* __restrict__ w_off0,
                               const float* __restrict__ w_off1,
                               const float* __restrict__ w0,
                               const float* __restrict__ w1,
                               float* __restrict__ wcT0, float* __restrict__ wcT1,
                               float* __restrict__ wdT0, float* __restrict__ wdT1) {
    int idx = blockIdx.x * 256 + threadIdx.x;      // 4 * 110592 total
    int which = idx / 110592;
    int r = idx - which * 110592;
    int k = r >> 12;
    int c = (r >> 6) & 63;
    int o = r & 63;
    const float* src;
    float* dst;
    int Co;
    switch (which) {
        case 0:  src = w_off0; dst = wcT0; Co = CO_OFF; break;
        case 1:  src = w_off1; dst = wcT1; Co = CO_OFF; break;
        case 2:  src = w0;     dst = wdT0; Co = 64;     break;
        default: src = w1;     dst = wdT1; Co = 64;     break;
    }
    float v = 0.f;
    if (o < Co) v = src[o * 1728 + c * 27 + k];
    dst[r] = v;
}

// ---------------------------------------------------------------------------
// NCTHW -> NHWC-style transpose: xT[pos*64 + c] = x[c*THW + pos]
// ---------------------------------------------------------------------------
__global__ void __launch_bounds__(256) transpose_kernel(
    const float* __restrict__ x, float* __restrict__ xT) {
    __shared__ float lx[64][65];
    const int tid = threadIdx.x;
    const int base = blockIdx.x * 64;      // t*4096 + h*64
    const int w = tid & 63, cg = tid >> 6; // cg 0..3
#pragma unroll
    for (int i = 0; i < 16; ++i) {
        const int c = cg * 16 + i;
        lx[c][w] = x[c * THW_ + base + w];
    }
    __syncthreads();
    const int c = tid & 63, j0 = tid >> 6;
#pragma unroll
    for (int j = 0; j < 16; ++j) {
        const int wp = j * 4 + j0;
        xT[(base + wp) * 64 + c] = lx[c][wp];
    }
}

// ---------------------------------------------------------------------------
// Plain 3x3x3 conv on NHWC input. Block = (t, h, w-half): 64 o x 32 w.
// Staging: c-fastest mapping (c4 = tid&15, wp = tid>>4) -> lanes 0..15 read
// 256 B contiguous (coalesced). GEMM thread (grp, obase, wbase) computes
// 4o x 2w over K=32 (split-K in-block, LDS-reduced at end).
// ---------------------------------------------------------------------------
__global__ void __launch_bounds__(512, 8) conv_off_kernel(
    const float* __restrict__ xT, const float* __restrict__ wT,
    const float* __restrict__ bias, float* __restrict__ out) {
    __shared__ float la[64][34];                  // 8.5 KB
    __shared__ __align__(16) float lwt[64][64];   // 16 KB
    const int tid = threadIdx.x;
    const int bid = blockIdx.x;
    const int t = bid >> 7, h = (bid >> 1) & 63, wh = bid & 1;
    const int wg = wh * 32;
    const int c4 = tid & 15;                      // c-fastest (coalesced global)
    const int wp = tid >> 4;                      // 0..31
    const int w = wg + wp;
    const int grp = tid >> 8;
    const int l = tid & 255;
    const int obase = (l >> 4) * 4;
    const int wbase = (l & 15) * 2;
    const int cbase = grp * 32;

    float acc[4][2] = {};
    const float4* s4 = reinterpret_cast<const float4*>(wT) + tid;  // +1024/tap

    for (int k = 0; k < KK_; ++k) {
        const int kt = k / 9 - 1, kh = (k / 3) % 3 - 1, kw = k % 3 - 1;
        const int ts = t + kt, hs = h + kh, wsr = w + kw;
        const bool ok = ((unsigned)ts < 7u) & ((unsigned)hs < 64u) & ((unsigned)wsr < 64u);
        float4 v = make_float4(0.f, 0.f, 0.f, 0.f);
        if (ok)
            v = *reinterpret_cast<const float4*>(xT + (ts * HW_ + hs * W_ + wsr) * 64 + c4 * 4);
        la[c4 * 4 + 0][wp] = v.x;
        la[c4 * 4 + 1][wp] = v.y;
        la[c4 * 4 + 2][wp] = v.z;
        la[c4 * 4 + 3][wp] = v.w;
        float4* l4 = reinterpret_cast<float4*>(&lwt[0][0]);
        l4[tid] = s4[0];
        l4[tid + 512] = s4[512];
        s4 += 1024;
        __syncthreads();

#pragma unroll 8
        for (int c = 0; c < 32; ++c) {
            const float2 av = *reinterpret_cast<const float2*>(&la[cbase + c][wbase]);
            const float4 wv = *reinterpret_cast<const float4*>(&lwt[cbase + c][obase]);
            acc[0][0] = fmaf(wv.x, av.x, acc[0][0]);
            acc[0][1] = fmaf(wv.x, av.y, acc[0][1]);
            acc[1][0] = fmaf(wv.y, av.x, acc[1][0]);
            acc[1][1] = fmaf(wv.y, av.y, acc[1][1]);
            acc[2][0] = fmaf(wv.z, av.x, acc[2][0]);
            acc[2][1] = fmaf(wv.z, av.y, acc[2][1]);
            acc[3][0] = fmaf(wv.w, av.x, acc[3][0]);
            acc[3][1] = fmaf(wv.w, av.y, acc[3][1]);
        }
        __syncthreads();
    }

    // split-K reduction (grp1 partials via lwt), then epilogue
    float4* red = reinterpret_cast<float4*>(&lwt[0][0]);
    if (grp == 1) {
        red[l * 2 + 0] = make_float4(acc[0][0], acc[1][0], acc[2][0], acc[3][0]);
        red[l * 2 + 1] = make_float4(acc[0][1], acc[1][1], acc[2][1], acc[3][1]);
    }
    __syncthreads();
    if (grp == 0) {
        const float4 r0 = red[l * 2 + 0];
        const float4 r1 = red[l * 2 + 1];
        acc[0][0] += r0.x; acc[1][0] += r0.y; acc[2][0] += r0.z; acc[3][0] += r0.w;
        acc[0][1] += r1.x; acc[1][1] += r1.y; acc[2][1] += r1.z; acc[3][1] += r1.w;
        const int sb = t * HW_ + h * W_ + wg + wbase;
#pragma unroll
        for (int io = 0; io < 4; ++io) {
            const int o = obase + io;
            if (o < CO_OFF) {
                const float b = bias[o];
                out[o * THW_ + sb + 0] = acc[io][0] + b;
                out[o * THW_ + sb + 1] = acc[io][1] + b;
            }
        }
    }
}

// ---------------------------------------------------------------------------
// Deformable conv on NHWC input. c-fastest staging: 16 threads share one w
// (same corners, broadcast offset loads), each gathers 4 contiguous channels
// x 4 corners as float4 loads -> fully coalesced 256 B per 16-lane group.
// MODE 0: write leaky_relu(y) in NHWC (yT). MODE 1: write y + resid in NCTHW.
// ---------------------------------------------------------------------------
template <int MODE>
__global__ void __launch_bounds__(512, 8) dcn_kernel(
    const float* __restrict__ xT, const float* __restrict__ off,
    const float* __restrict__ wT, const float* __restrict__ resid,
    float* __restrict__ out) {
    __shared__ float la[64][34];
    __shared__ __align__(16) float lwt[64][64];
    const int tid = threadIdx.x;
    const int bid = blockIdx.x;
    const int t = bid >> 7, h = (bid >> 1) & 63, wh = bid & 1;
    const int wg = wh * 32;
    const int c4 = tid & 15;                      // c-fastest (coalesced global)
    const int wp = tid >> 4;                      // 0..31
    const int w = wg + wp;
    const int grp = tid >> 8;
    const int l = tid & 255;
    const int obase = (l >> 4) * 4;
    const int wbase = (l & 15) * 2;
    const int cbase = grp * 32;

    float acc[4][2] = {};
    const int sidx = t * HW_ + h * W_ + w;
    const float* offp = off + sidx;                                // +2*THW_/tap
    const float4* s4 = reinterpret_cast<const float4*>(wT) + tid;  // +1024/tap

    for (int k = 0; k < KK_; ++k) {
        const int kt = k / 9 - 1, kh = (k / 3) % 3 - 1, kw = k % 3 - 1;
        const int ts = t + kt;
        const bool tok = (unsigned)ts < 7u;
        const int tcb = ts < 0 ? 0 : (ts > 6 ? 6 : ts);
        const float oh = offp[0];
        const float ow = offp[THW_];
        offp += 2 * THW_;
        const float ph = (float)(h + kh) + oh;
        const float pw = (float)(w + kw) + ow;
        const float h0f = floorf(ph), w0f = floorf(pw);
        const float fh = ph - h0f, fw = pw - w0f;
        const int h0 = (int)h0f, w0i = (int)w0f;
        const int h1 = h0 + 1, w1i = w0i + 1;
        const bool h0k = (unsigned)h0 < 64u, h1k = (unsigned)h1 < 64u;
        const bool w0k = (unsigned)w0i < 64u, w1k = (unsigned)w1i < 64u;
        const int tb = tcb * HW_;
        const int h0c = (h0 < 0 ? 0 : (h0 > 63 ? 63 : h0)) * W_;
        const int h1c = (h1 < 0 ? 0 : (h1 > 63 ? 63 : h1)) * W_;
        const int w0c = w0i < 0 ? 0 : (w0i > 63 ? 63 : w0i);
        const int w1c = w1i < 0 ? 0 : (w1i > 63 ? 63 : w1i);
        const float f0 = (tok && h0k && w0k) ? (1.f - fh) * (1.f - fw) : 0.f;
        const float f1 = (tok && h0k && w1k) ? (1.f - fh) * fw : 0.f;
        const float f2 = (tok && h1k && w0k) ? fh * (1.f - fw) : 0.f;
        const float f3 = (tok && h1k && w1k) ? fh * fw : 0.f;
        const int cb = c4 * 4;
        const float4 A = *reinterpret_cast<const float4*>(xT + (tb + h0c + w0c) * 64 + cb);
        const float4 B = *reinterpret_cast<const float4*>(xT + (tb + h0c + w1c) * 64 + cb);
        const float4 C = *reinterpret_cast<const float4*>(xT + (tb + h1c + w0c) * 64 + cb);
        const float4 D = *reinterpret_cast<const float4*>(xT + (tb + h1c + w1c) * 64 + cb);
        la[cb + 0][wp] = fmaf(f0, A.x, fmaf(f1, B.x, fmaf(f2, C.x, f3 * D.x)));
        la[cb + 1][wp] = fmaf(f0, A.y, fmaf(f1, B.y, fmaf(f2, C.y, f3 * D.y)));
        la[cb + 2][wp] = fmaf(f0, A.z, fmaf(f1, B.z, fmaf(f2, C.z, f3 * D.z)));
        la[cb + 3][wp] = fmaf(f0, A.w, fmaf(f1, B.w, fmaf(f2, C.w, f3 * D.w)));
        float4* l4 = reinterpret_cast<float4*>(&lwt[0][0]);
        l4[tid] = s4[0];
        l4[tid + 512] = s4[512];
        s4 += 1024;
        __syncthreads();

#pragma unroll 8
        for (int c = 0; c < 32; ++c) {
            const float2 av = *reinterpret_cast<const float2*>(&la[cbase + c][wbase]);
            const float4 wv = *reinterpret_cast<const float4*>(&lwt[cbase + c][obase]);
            acc[0][0] = fmaf(wv.x, av.x, acc[0][0]);
            acc[0][1] = fmaf(wv.x, av.y, acc[0][1]);
            acc[1][0] = fmaf(wv.y, av.x, acc[1][0]);
            acc[1][1] = fmaf(wv.y, av.y, acc[1][1]);
            acc[2][0] = fmaf(wv.z, av.x, acc[2][0]);
            acc[2][1] = fmaf(wv.z, av.y, acc[2][1]);
            acc[3][0] = fmaf(wv.w, av.x, acc[3][0]);
            acc[3][1] = fmaf(wv.w, av.y, acc[3][1]);
        }
        __syncthreads();
    }

    // split-K reduction
    float4* red = reinterpret_cast<float4*>(&lwt[0][0]);
    if (grp == 1) {
        red[l * 2 + 0] = make_float4(acc[0][0], acc[1][0], acc[2][0], acc[3][0]);
        red[l * 2 + 1] = make_float4(acc[0][1], acc[1][1], acc[2][1], acc[3][1]);
    }
    __syncthreads();
    if (grp == 0) {
        const float4 r0 = red[l * 2 + 0];
        const float4 r1 = red[l * 2 + 1];
        acc[0][0] += r0.x; acc[1][0] += r0.y; acc[2][0] += r0.z; acc[3][0] += r0.w;
        acc[0][1] += r1.x; acc[1][1] += r1.y; acc[2][1] += r1.z; acc[3][1] += r1.w;
        const int posb = t * HW_ + h * W_ + wg + wbase;
        if (MODE == 0) {
            // NHWC output with leaky-relu
#pragma unroll
            for (int iw = 0; iw < 2; ++iw) {
                float v0 = acc[0][iw], v1 = acc[1][iw], v2 = acc[2][iw], v3 = acc[3][iw];
                v0 = v0 > 0.f ? v0 : 0.1f * v0;
                v1 = v1 > 0.f ? v1 : 0.1f * v1;
                v2 = v2 > 0.f ? v2 : 0.1f * v2;
                v3 = v3 > 0.f ? v3 : 0.1f * v3;
                *reinterpret_cast<float4*>(out + (posb + iw) * 64 + obase) =
                    make_float4(v0, v1, v2, v3);
            }
        } else {
            // NCTHW output + residual
#pragma unroll
            for (int io = 0; io < 4; ++io) {
                const int o = obase + io;
                const float* r2 = resid + o * THW_ + posb;
                float* dst = out + o * THW_ + posb;
                dst[0] = acc[io][0] + r2[0];
                dst[1] = acc[io][1] + r2[1];
            }
        }
    }
}

// ---------------------------------------------------------------------------
extern "C" void kernel_launch(void* const* d_in, const int* in_sizes, int n_in,
                              void* d_out, int out_size, void* d_ws, size_t ws_size,
                              hipStream_t stream) {
    (void)in_sizes; (void)n_in; (void)out_size; (void)ws_size;
    const float* x      = (const float*)d_in[0];
    const float* w_off0 = (const float*)d_in[1];
    const float* b_off0 = (const float*)d_in[2];
    const float* w0     = (const float*)d_in[3];
    const float* w_off1 = (const float*)d_in[4];
    const float* b_off1 = (const float*)d_in[5];
    const float* w1     = (const float*)d_in[6];
    float* out = (float*)d_out;

    float* ws = (float*)d_ws;
    float* xT      = ws;                       // 64*28672 (NHWC x)
    float* yT      = xT + 64 * THW_;           // 64*28672 (NHWC y)
    float* off_buf = yT + 64 * THW_;           // 54*28672
    float* wcT0 = off_buf + CO_OFF * THW_;     // 27*64*64 each
    float* wcT1 = wcT0 + 27 * 4096;
    float* wdT0 = wcT1 + 27 * 4096;
    float* wdT1 = wdT0 + 27 * 4096;

    prep_wt_kernel<<<1728, 256, 0, stream>>>(w_off0, w_off1, w0, w1,
                                             wcT0, wcT1, wdT0, wdT1);
    transpose_kernel<<<448, 256, 0, stream>>>(x, xT);
    conv_off_kernel<<<896, 512, 0, stream>>>(xT, wcT0, b_off0, off_buf);
    dcn_kernel<0><<<896, 512, 0, stream>>>(xT, off_buf, wdT0, nullptr, yT);
    conv_off_kernel<<<896, 512, 0, stream>>>(yT, wcT1, b_off1, off_buf);
    dcn_kernel<1><<<896, 512, 0, stream>>>(yT, off_buf, wdT1, x, out);
}

// Round 12
// 265.906 us; speedup vs baseline: 2.4121x; 2.3740x over previous
//
#include <hip/hip_runtime.h>

#define T_ 7
#define H_ 64
#define W_ 64
#define KK_ 27
#define HW_ 4096
#define THW_ 28672
#define CO_OFF 54
#define OFFSTR 56   // offT row stride (floats), 8B-aligned

using frag_ab = __attribute__((ext_vector_type(8))) short;  // 8 bf16
using f32x4   = __attribute__((ext_vector_type(4))) float;  // 4 fp32 acc

__device__ __forceinline__ unsigned short f2bf(float v) {
    unsigned u = __float_as_uint(v);
    unsigned r = u + 0x7FFFu + ((u >> 16) & 1u);
    return (unsigned short)(r >> 16);
}
__device__ __forceinline__ float bf2f(unsigned short h) {
    return __uint_as_float(((unsigned)h) << 16);
}
__device__ __forceinline__ void split_bf(float v, unsigned short& hi, unsigned short& lo) {
    hi = f2bf(v);
    lo = f2bf(v - bf2f(hi));
}

// ---------------------------------------------------------------------------
// Weight prep: split each conv weight into bf16 hi/lo planes, laid out
// [tap][plane][o][c] (c contiguous for K-fragment b128 reads). o padded to 64.
// ---------------------------------------------------------------------------
__global__ void prep_wt_kernel(const float* __restrict__ w_off0,
                               const float* __restrict__ w_off1,
                               const float* __restrict__ w0,
                               const float* __restrict__ w1,
                               unsigned short* __restrict__ wc0,
                               unsigned short* __restrict__ wc1,
                               unsigned short* __restrict__ wd0,
                               unsigned short* __restrict__ wd1) {
    int idx = blockIdx.x * 256 + threadIdx.x;   // 4 * 110592
    int which = idx / 110592;
    int r = idx - which * 110592;
    int tap = r >> 12;
    int o = (r >> 6) & 63;
    int c = r & 63;
    const float* src;
    unsigned short* dst;
    int Co;
    switch (which) {
        case 0:  src = w_off0; dst = wc0; Co = CO_OFF; break;
        case 1:  src = w_off1; dst = wc1; Co = CO_OFF; break;
        case 2:  src = w0;     dst = wd0; Co = 64;     break;
        default: src = w1;     dst = wd1; Co = 64;     break;
    }
    float v = 0.f;
    if (o < Co) v = src[o * 1728 + c * 27 + tap];
    unsigned short hi, lo;
    split_bf(v, hi, lo);
    dst[tap * 8192 + 0 * 4096 + o * 64 + c] = hi;
    dst[tap * 8192 + 1 * 4096 + o * 64 + c] = lo;
}

// ---------------------------------------------------------------------------
// NCTHW -> NHWC transpose: xT[pos*64 + c] = x[c*THW + pos]
// ---------------------------------------------------------------------------
__global__ void __launch_bounds__(256) transpose_kernel(
    const float* __restrict__ x, float* __restrict__ xT) {
    __shared__ float lx[64][65];
    const int tid = threadIdx.x;
    const int base = blockIdx.x * 64;
    const int w = tid & 63, cg = tid >> 6;
#pragma unroll
    for (int i = 0; i < 16; ++i) {
        const int c = cg * 16 + i;
        lx[c][w] = x[c * THW_ + base + w];
    }
    __syncthreads();
    const int c = tid & 63, j0 = tid >> 6;
#pragma unroll
    for (int j = 0; j < 16; ++j) {
        const int wp = j * 4 + j0;
        xT[(base + wp) * 64 + c] = lx[c][wp];
    }
}

// ---------------------------------------------------------------------------
// MFMA GEMM core shared shape: block = (t,h,w-half): 32 pos x 64 o, K=64/tap.
// 8 waves = 2 w-tiles x 4 o-tiles, acc = one 16x16 f32x4 per wave.
// LDS: A[2 planes][32 w][64 c] bf16, B[2 planes][64 o][64 c] bf16,
// XOR-swizzled (col ^= (row&7)<<3 ushorts) for conflict-free b128 frag reads.
// Split-bf16: 3 mfma per K-step (hh, hl, lh) -> ~2^-16 rel error.
// ---------------------------------------------------------------------------

// Plain conv producing offsets, output NHWC offT[pos*56 + ch] (+bias, ch<54).
__global__ void __launch_bounds__(512, 8) conv_off_kernel(
    const float* __restrict__ xT, const unsigned short* __restrict__ wB,
    const float* __restrict__ bias, float* __restrict__ offT) {
    __shared__ __align__(16) unsigned short A_l[2][32][64];
    __shared__ __align__(16) unsigned short B_l[2][64][64];
    const int tid = threadIdx.x;
    const int bid = blockIdx.x;
    const int t = bid >> 7, h = (bid >> 1) & 63, wh = bid & 1;
    const int wg = wh * 32;
    const int c4 = tid & 15;          // staging: 4 channels
    const int wp = tid >> 4;          // staging: w position 0..31
    const int lane = tid & 63, wid = tid >> 6;
    const int wtile = wid & 1, otile = wid >> 1;
    const int ln15 = lane & 15, kg = lane >> 4;
    const int arow = wtile * 16 + ln15;
    const int brow = otile * 16 + ln15;
    const int posb = t * HW_ + h * W_ + wg;

    f32x4 acc = {0.f, 0.f, 0.f, 0.f};

    for (int k = 0; k < KK_; ++k) {
        const int kt = k / 9 - 1, kh = (k / 3) % 3 - 1, kw = k % 3 - 1;
        // ---- stage A (shifted input, zero-pad), split to hi/lo bf16 ----
        const int ts = t + kt, hs = h + kh, wsr = wg + wp + kw;
        const bool ok = ((unsigned)ts < 7u) & ((unsigned)hs < 64u) & ((unsigned)wsr < 64u);
        float4 v = make_float4(0.f, 0.f, 0.f, 0.f);
        if (ok)
            v = *reinterpret_cast<const float4*>(xT + (ts * HW_ + hs * W_ + wsr) * 64 + c4 * 4);
        ushort4 hv, lv;
        split_bf(v.x, hv.x, lv.x); split_bf(v.y, hv.y, lv.y);
        split_bf(v.z, hv.z, lv.z); split_bf(v.w, hv.w, lv.w);
        const int ci = (c4 * 4) ^ ((wp & 7) << 3);
        *reinterpret_cast<ushort4*>(&A_l[0][wp][ci]) = hv;
        *reinterpret_cast<ushort4*>(&A_l[1][wp][ci]) = lv;
        // ---- stage B (pre-split weights), 2 passes of 512 b128 chunks ----
        const unsigned short* wt = wB + k * 8192;
#pragma unroll
        for (int p = 0; p < 2; ++p) {
            const int u = p * 512 + tid;
            const int pl = u >> 9, o = (u >> 3) & 63, c8 = u & 7;
            const int bi = (c8 * 8) ^ ((o & 7) << 3);
            *reinterpret_cast<frag_ab*>(&B_l[pl][o][bi]) =
                *reinterpret_cast<const frag_ab*>(wt + pl * 4096 + o * 64 + c8 * 8);
        }
        __syncthreads();
        // ---- MFMA: K=64 as 2 x K=32, split-bf16 (3 mfma each) ----
#pragma unroll
        for (int ks = 0; ks < 2; ++ks) {
            const int ka = ks * 32 + kg * 8;
            const frag_ab ah = *reinterpret_cast<const frag_ab*>(&A_l[0][arow][ka ^ ((arow & 7) << 3)]);
            const frag_ab al = *reinterpret_cast<const frag_ab*>(&A_l[1][arow][ka ^ ((arow & 7) << 3)]);
            const frag_ab bh = *reinterpret_cast<const frag_ab*>(&B_l[0][brow][ka ^ ((brow & 7) << 3)]);
            const frag_ab bl = *reinterpret_cast<const frag_ab*>(&B_l[1][brow][ka ^ ((brow & 7) << 3)]);
            acc = __builtin_amdgcn_mfma_f32_16x16x32_bf16(ah, bh, acc, 0, 0, 0);
            acc = __builtin_amdgcn_mfma_f32_16x16x32_bf16(ah, bl, acc, 0, 0, 0);
            acc = __builtin_amdgcn_mfma_f32_16x16x32_bf16(al, bh, acc, 0, 0, 0);
        }
        __syncthreads();
    }

    // epilogue: D col = lane&15 (o), row = kg*4+reg (w) -> NHWC offT
    const int o = otile * 16 + ln15;
    if (o < CO_OFF) {
        const float b = bias[o];
#pragma unroll
        for (int reg = 0; reg < 4; ++reg) {
            const int wl_ = wtile * 16 + kg * 4 + reg;
            offT[(posb + wl_) * OFFSTR + o] = acc[reg] + b;
        }
    }
}

// Deformable conv. MODE 0: leaky_relu -> NHWC yT. MODE 1: +resid -> NCTHW out.
template <int MODE>
__global__ void __launch_bounds__(512, 8) dcn_kernel(
    const float* __restrict__ xT, const float* __restrict__ offT,
    const unsigned short* __restrict__ wB, const float* __restrict__ resid,
    float* __restrict__ out) {
    __shared__ __align__(16) unsigned short A_l[2][32][64];
    __shared__ __align__(16) unsigned short B_l[2][64][64];
    __shared__ float ep[32][65];
    const int tid = threadIdx.x;
    const int bid = blockIdx.x;
    const int t = bid >> 7, h = (bid >> 1) & 63, wh = bid & 1;
    const int wg = wh * 32;
    const int c4 = tid & 15;
    const int wp = tid >> 4;
    const int lane = tid & 63, wid = tid >> 6;
    const int wtile = wid & 1, otile = wid >> 1;
    const int ln15 = lane & 15, kg = lane >> 4;
    const int arow = wtile * 16 + ln15;
    const int brow = otile * 16 + ln15;
    const int posb = t * HW_ + h * W_ + wg;

    f32x4 acc = {0.f, 0.f, 0.f, 0.f};
    const int w = wg + wp;
    const float* offp = offT + (posb + wp) * OFFSTR;

    for (int k = 0; k < KK_; ++k) {
        const int kt = k / 9 - 1, kh = (k / 3) % 3 - 1, kw = k % 3 - 1;
        // ---- bilinear corners (16 threads per w share math via broadcast) --
        const int ts = t + kt;
        const bool tok = (unsigned)ts < 7u;
        const int tcb = ts < 0 ? 0 : (ts > 6 ? 6 : ts);
        const float2 of2 = *reinterpret_cast<const float2*>(offp + 2 * k);
        const float ph = (float)(h + kh) + of2.x;
        const float pw = (float)(w + kw) + of2.y;
        const float h0f = floorf(ph), w0f = floorf(pw);
        const float fh = ph - h0f, fw = pw - w0f;
        const int h0 = (int)h0f, w0i = (int)w0f;
        const int h1 = h0 + 1, w1i = w0i + 1;
        const bool h0k = (unsigned)h0 < 64u, h1k = (unsigned)h1 < 64u;
        const bool w0k = (unsigned)w0i < 64u, w1k = (unsigned)w1i < 64u;
        const int tb = tcb * HW_;
        const int h0c = (h0 < 0 ? 0 : (h0 > 63 ? 63 : h0)) * W_;
        const int h1c = (h1 < 0 ? 0 : (h1 > 63 ? 63 : h1)) * W_;
        const int w0c = w0i < 0 ? 0 : (w0i > 63 ? 63 : w0i);
        const int w1c = w1i < 0 ? 0 : (w1i > 63 ? 63 : w1i);
        const float f0 = (tok && h0k && w0k) ? (1.f - fh) * (1.f - fw) : 0.f;
        const float f1 = (tok && h0k && w1k) ? (1.f - fh) * fw : 0.f;
        const float f2 = (tok && h1k && w0k) ? fh * (1.f - fw) : 0.f;
        const float f3 = (tok && h1k && w1k) ? fh * fw : 0.f;
        const int cb = c4 * 4;
        const float4 A = *reinterpret_cast<const float4*>(xT + (tb + h0c + w0c) * 64 + cb);
        const float4 B = *reinterpret_cast<const float4*>(xT + (tb + h0c + w1c) * 64 + cb);
        const float4 C = *reinterpret_cast<const float4*>(xT + (tb + h1c + w0c) * 64 + cb);
        const float4 D = *reinterpret_cast<const float4*>(xT + (tb + h1c + w1c) * 64 + cb);
        float s0 = fmaf(f0, A.x, fmaf(f1, B.x, fmaf(f2, C.x, f3 * D.x)));
        float s1 = fmaf(f0, A.y, fmaf(f1, B.y, fmaf(f2, C.y, f3 * D.y)));
        float s2 = fmaf(f0, A.z, fmaf(f1, B.z, fmaf(f2, C.z, f3 * D.z)));
        float s3 = fmaf(f0, A.w, fmaf(f1, B.w, fmaf(f2, C.w, f3 * D.w)));
        ushort4 hv, lv;
        split_bf(s0, hv.x, lv.x); split_bf(s1, hv.y, lv.y);
        split_bf(s2, hv.z, lv.z); split_bf(s3, hv.w, lv.w);
        const int ci = (cb) ^ ((wp & 7) << 3);
        *reinterpret_cast<ushort4*>(&A_l[0][wp][ci]) = hv;
        *reinterpret_cast<ushort4*>(&A_l[1][wp][ci]) = lv;
        const unsigned short* wt = wB + k * 8192;
#pragma unroll
        for (int p = 0; p < 2; ++p) {
            const int u = p * 512 + tid;
            const int pl = u >> 9, o = (u >> 3) & 63, c8 = u & 7;
            const int bi = (c8 * 8) ^ ((o & 7) << 3);
            *reinterpret_cast<frag_ab*>(&B_l[pl][o][bi]) =
                *reinterpret_cast<const frag_ab*>(wt + pl * 4096 + o * 64 + c8 * 8);
        }
        __syncthreads();
#pragma unroll
        for (int ks = 0; ks < 2; ++ks) {
            const int ka = ks * 32 + kg * 8;
            const frag_ab ah = *reinterpret_cast<const frag_ab*>(&A_l[0][arow][ka ^ ((arow & 7) << 3)]);
            const frag_ab al = *reinterpret_cast<const frag_ab*>(&A_l[1][arow][ka ^ ((arow & 7) << 3)]);
            const frag_ab bh = *reinterpret_cast<const frag_ab*>(&B_l[0][brow][ka ^ ((brow & 7) << 3)]);
            const frag_ab bl = *reinterpret_cast<const frag_ab*>(&B_l[1][brow][ka ^ ((brow & 7) << 3)]);
            acc = __builtin_amdgcn_mfma_f32_16x16x32_bf16(ah, bh, acc, 0, 0, 0);
            acc = __builtin_amdgcn_mfma_f32_16x16x32_bf16(ah, bl, acc, 0, 0, 0);
            acc = __builtin_amdgcn_mfma_f32_16x16x32_bf16(al, bh, acc, 0, 0, 0);
        }
        __syncthreads();
    }

    const int o = otile * 16 + ln15;
    if (MODE == 0) {
        // leaky-relu -> NHWC yT
#pragma unroll
        for (int reg = 0; reg < 4; ++reg) {
            const int wl_ = wtile * 16 + kg * 4 + reg;
            float v = acc[reg];
            v = v > 0.f ? v : 0.1f * v;
            out[(posb + wl_) * 64 + o] = v;
        }
    } else {
        // transpose via LDS, then coalesced NCTHW + residual
#pragma unroll
        for (int reg = 0; reg < 4; ++reg) {
            const int wl_ = wtile * 16 + kg * 4 + reg;
            ep[wl_][o] = acc[reg];
        }
        __syncthreads();
        const int w2 = tid & 31, og = tid >> 5;  // og 0..15
#pragma unroll
        for (int i = 0; i < 4; ++i) {
            const int oc = og + i * 16;
            out[oc * THW_ + posb + w2] = ep[w2][oc] + resid[oc * THW_ + posb + w2];
        }
    }
}

// ---------------------------------------------------------------------------
extern "C" void kernel_launch(void* const* d_in, const int* in_sizes, int n_in,
                              void* d_out, int out_size, void* d_ws, size_t ws_size,
                              hipStream_t stream) {
    (void)in_sizes; (void)n_in; (void)out_size; (void)ws_size;
    const float* x      = (const float*)d_in[0];
    const float* w_off0 = (const float*)d_in[1];
    const float* b_off0 = (const float*)d_in[2];
    const float* w0     = (const float*)d_in[3];
    const float* w_off1 = (const float*)d_in[4];
    const float* b_off1 = (const float*)d_in[5];
    const float* w1     = (const float*)d_in[6];
    float* out = (float*)d_out;

    float* ws = (float*)d_ws;
    float* xT   = ws;                          // 64*THW
    float* yT   = xT + 64 * THW_;              // 64*THW
    float* offT = yT + 64 * THW_;              // THW*56
    unsigned short* wc0 = (unsigned short*)(offT + THW_ * OFFSTR);  // 27*2*64*64 each
    unsigned short* wc1 = wc0 + 221184;
    unsigned short* wd0 = wc1 + 221184;
    unsigned short* wd1 = wd0 + 221184;

    prep_wt_kernel<<<1728, 256, 0, stream>>>(w_off0, w_off1, w0, w1,
                                             wc0, wc1, wd0, wd1);
    transpose_kernel<<<448, 256, 0, stream>>>(x, xT);
    conv_off_kernel<<<896, 512, 0, stream>>>(xT, wc0, b_off0, offT);
    dcn_kernel<0><<<896, 512, 0, stream>>>(xT, offT, wd0, nullptr, yT);
    conv_off_kernel<<<896, 512, 0, stream>>>(yT, wc1, b_off1, offT);
    dcn_kernel<1><<<896, 512, 0, stream>>>(yT, offT, wd1, x, out);
}

// Round 13
// 265.381 us; speedup vs baseline: 2.4169x; 1.0020x over previous
//
#include <hip/hip_runtime.h>

#define T_ 7
#define H_ 64
#define W_ 64
#define KK_ 27
#define HW_ 4096
#define THW_ 28672
#define CO_OFF 54
#define OFFSTR 56   // offT row stride (floats), 8B-aligned

using frag_ab = __attribute__((ext_vector_type(8))) short;  // 8 bf16
using f32x4   = __attribute__((ext_vector_type(4))) float;  // 4 fp32 acc

__device__ __forceinline__ unsigned short f2bf(float v) {
    unsigned u = __float_as_uint(v);
    unsigned r = u + 0x7FFFu + ((u >> 16) & 1u);
    return (unsigned short)(r >> 16);
}
__device__ __forceinline__ float bf2f(unsigned short h) {
    return __uint_as_float(((unsigned)h) << 16);
}
// rounded split (used once, in weight prep — off the hot path)
__device__ __forceinline__ void split_bf(float v, unsigned short& hi, unsigned short& lo) {
    hi = f2bf(v);
    lo = f2bf(v - bf2f(hi));
}
// truncation split (hot path): 4 VALU ops/value. hi-residual <= 2^-7|v| is
// captured exactly in fp32, lo truncation leaves ~2^-14|v| scheme error.
__device__ __forceinline__ void split_tr(float v, unsigned short& hi, unsigned short& lo) {
    unsigned u = __float_as_uint(v);
    hi = (unsigned short)(u >> 16);
    float r = v - __uint_as_float(u & 0xFFFF0000u);
    lo = (unsigned short)(__float_as_uint(r) >> 16);
}

// ---------------------------------------------------------------------------
// Weight prep: split each conv weight into bf16 hi/lo planes, laid out
// [tap][plane][o][c] (c contiguous for K-fragment b128 reads). o padded to 64.
// ---------------------------------------------------------------------------
__global__ void prep_wt_kernel(const float* __restrict__ w_off0,
                               const float* __restrict__ w_off1,
                               const float* __restrict__ w0,
                               const float* __restrict__ w1,
                               unsigned short* __restrict__ wc0,
                               unsigned short* __restrict__ wc1,
                               unsigned short* __restrict__ wd0,
                               unsigned short* __restrict__ wd1) {
    int idx = blockIdx.x * 256 + threadIdx.x;   // 4 * 110592
    int which = idx / 110592;
    int r = idx - which * 110592;
    int tap = r >> 12;
    int o = (r >> 6) & 63;
    int c = r & 63;
    const float* src;
    unsigned short* dst;
    int Co;
    switch (which) {
        case 0:  src = w_off0; dst = wc0; Co = CO_OFF; break;
        case 1:  src = w_off1; dst = wc1; Co = CO_OFF; break;
        case 2:  src = w0;     dst = wd0; Co = 64;     break;
        default: src = w1;     dst = wd1; Co = 64;     break;
    }
    float v = 0.f;
    if (o < Co) v = src[o * 1728 + c * 27 + tap];
    unsigned short hi, lo;
    split_bf(v, hi, lo);
    dst[tap * 8192 + 0 * 4096 + o * 64 + c] = hi;
    dst[tap * 8192 + 1 * 4096 + o * 64 + c] = lo;
}

// ---------------------------------------------------------------------------
// NCTHW -> NHWC transpose: xT[pos*64 + c] = x[c*THW + pos]
// ---------------------------------------------------------------------------
__global__ void __launch_bounds__(256) transpose_kernel(
    const float* __restrict__ x, float* __restrict__ xT) {
    __shared__ float lx[64][65];
    const int tid = threadIdx.x;
    const int base = blockIdx.x * 64;
    const int w = tid & 63, cg = tid >> 6;
#pragma unroll
    for (int i = 0; i < 16; ++i) {
        const int c = cg * 16 + i;
        lx[c][w] = x[c * THW_ + base + w];
    }
    __syncthreads();
    const int c = tid & 63, j0 = tid >> 6;
#pragma unroll
    for (int j = 0; j < 16; ++j) {
        const int wp = j * 4 + j0;
        xT[(base + wp) * 64 + c] = lx[c][wp];
    }
}

// ---------------------------------------------------------------------------
// MFMA GEMM core shared shape: block = (t,h,w-half): 32 pos x 64 o, K=64/tap.
// 8 waves = 2 w-tiles x 4 o-tiles, acc = one 16x16 f32x4 per wave.
// LDS: A[2 planes][32 w][64 c] bf16, B[2 planes][64 o][64 c] bf16,
// XOR-swizzled (col ^= (row&7)<<3 ushorts) for conflict-free b128 frag reads.
// Split-bf16: 3 mfma per K-step (hh, hl, lh) -> ~2^-14 rel error (trunc split).
// ---------------------------------------------------------------------------

// Plain conv producing offsets, output NHWC offT[pos*56 + ch] (+bias, ch<54).
__global__ void __launch_bounds__(512, 8) conv_off_kernel(
    const float* __restrict__ xT, const unsigned short* __restrict__ wB,
    const float* __restrict__ bias, float* __restrict__ offT) {
    __shared__ __align__(16) unsigned short A_l[2][32][64];
    __shared__ __align__(16) unsigned short B_l[2][64][64];
    const int tid = threadIdx.x;
    const int bid = blockIdx.x;
    const int t = bid >> 7, h = (bid >> 1) & 63, wh = bid & 1;
    const int wg = wh * 32;
    const int c4 = tid & 15;          // staging: 4 channels
    const int wp = tid >> 4;          // staging: w position 0..31
    const int lane = tid & 63, wid = tid >> 6;
    const int wtile = wid & 1, otile = wid >> 1;
    const int ln15 = lane & 15, kg = lane >> 4;
    const int arow = wtile * 16 + ln15;
    const int brow = otile * 16 + ln15;
    const int posb = t * HW_ + h * W_ + wg;
    // B-staging decode (constant per thread)
    const int bo = (tid >> 3) & 63, bc8 = tid & 7;
    const int bi = (bc8 * 8) ^ ((bo & 7) << 3);

    f32x4 acc = {0.f, 0.f, 0.f, 0.f};

    for (int k = 0; k < KK_; ++k) {
        const int kt = k / 9 - 1, kh = (k / 3) % 3 - 1, kw = k % 3 - 1;
        // ---- stage A (shifted input, zero-pad), trunc-split to hi/lo ----
        const int ts = t + kt, hs = h + kh, wsr = wg + wp + kw;
        const bool ok = ((unsigned)ts < 7u) & ((unsigned)hs < 64u) & ((unsigned)wsr < 64u);
        float4 v = make_float4(0.f, 0.f, 0.f, 0.f);
        if (ok)
            v = *reinterpret_cast<const float4*>(xT + (ts * HW_ + hs * W_ + wsr) * 64 + c4 * 4);
        ushort4 hv, lv;
        split_tr(v.x, hv.x, lv.x); split_tr(v.y, hv.y, lv.y);
        split_tr(v.z, hv.z, lv.z); split_tr(v.w, hv.w, lv.w);
        const int ci = (c4 * 4) ^ ((wp & 7) << 3);
        *reinterpret_cast<ushort4*>(&A_l[0][wp][ci]) = hv;
        *reinterpret_cast<ushort4*>(&A_l[1][wp][ci]) = lv;
        // ---- stage B (pre-split weights) ----
        const unsigned short* wt = wB + k * 8192 + bo * 64 + bc8 * 8;
        *reinterpret_cast<frag_ab*>(&B_l[0][bo][bi]) =
            *reinterpret_cast<const frag_ab*>(wt);
        *reinterpret_cast<frag_ab*>(&B_l[1][bo][bi]) =
            *reinterpret_cast<const frag_ab*>(wt + 4096);
        __syncthreads();
        // ---- MFMA: K=64 as 2 x K=32, split-bf16 (3 mfma each) ----
#pragma unroll
        for (int ks = 0; ks < 2; ++ks) {
            const int ka = ks * 32 + kg * 8;
            const frag_ab ah = *reinterpret_cast<const frag_ab*>(&A_l[0][arow][ka ^ ((arow & 7) << 3)]);
            const frag_ab al = *reinterpret_cast<const frag_ab*>(&A_l[1][arow][ka ^ ((arow & 7) << 3)]);
            const frag_ab bh = *reinterpret_cast<const frag_ab*>(&B_l[0][brow][ka ^ ((brow & 7) << 3)]);
            const frag_ab bl = *reinterpret_cast<const frag_ab*>(&B_l[1][brow][ka ^ ((brow & 7) << 3)]);
            acc = __builtin_amdgcn_mfma_f32_16x16x32_bf16(ah, bh, acc, 0, 0, 0);
            acc = __builtin_amdgcn_mfma_f32_16x16x32_bf16(ah, bl, acc, 0, 0, 0);
            acc = __builtin_amdgcn_mfma_f32_16x16x32_bf16(al, bh, acc, 0, 0, 0);
        }
        __syncthreads();
    }

    // epilogue: D col = lane&15 (o), row = kg*4+reg (w) -> NHWC offT
    const int o = otile * 16 + ln15;
    if (o < CO_OFF) {
        const float b = bias[o];
#pragma unroll
        for (int reg = 0; reg < 4; ++reg) {
            const int wl_ = wtile * 16 + kg * 4 + reg;
            offT[(posb + wl_) * OFFSTR + o] = acc[reg] + b;
        }
    }
}

// Deformable conv. MODE 0: leaky_relu -> NHWC yT. MODE 1: +resid -> NCTHW out.
template <int MODE>
__global__ void __launch_bounds__(512, 8) dcn_kernel(
    const float* __restrict__ xT, const float* __restrict__ offT,
    const unsigned short* __restrict__ wB, const float* __restrict__ resid,
    float* __restrict__ out) {
    __shared__ __align__(16) unsigned short A_l[2][32][64];
    __shared__ __align__(16) unsigned short B_l[2][64][64];
    __shared__ float ep[32][65];
    const int tid = threadIdx.x;
    const int bid = blockIdx.x;
    const int t = bid >> 7, h = (bid >> 1) & 63, wh = bid & 1;
    const int wg = wh * 32;
    const int c4 = tid & 15;
    const int wp = tid >> 4;
    const int lane = tid & 63, wid = tid >> 6;
    const int wtile = wid & 1, otile = wid >> 1;
    const int ln15 = lane & 15, kg = lane >> 4;
    const int arow = wtile * 16 + ln15;
    const int brow = otile * 16 + ln15;
    const int posb = t * HW_ + h * W_ + wg;
    const int bo = (tid >> 3) & 63, bc8 = tid & 7;
    const int bi = (bc8 * 8) ^ ((bo & 7) << 3);

    f32x4 acc = {0.f, 0.f, 0.f, 0.f};
    const int w = wg + wp;
    const float* offp = offT + (posb + wp) * OFFSTR;

    for (int k = 0; k < KK_; ++k) {
        const int kt = k / 9 - 1, kh = (k / 3) % 3 - 1, kw = k % 3 - 1;
        // ---- bilinear corners (16 threads per w share math via broadcast) --
        const int ts = t + kt;
        const bool tok = (unsigned)ts < 7u;
        const int tcb = ts < 0 ? 0 : (ts > 6 ? 6 : ts);
        const float2 of2 = *reinterpret_cast<const float2*>(offp + 2 * k);
        const float ph = (float)(h + kh) + of2.x;
        const float pw = (float)(w + kw) + of2.y;
        const float h0f = floorf(ph), w0f = floorf(pw);
        const float fh = ph - h0f, fw = pw - w0f;
        const int h0 = (int)h0f, w0i = (int)w0f;
        const int h1 = h0 + 1, w1i = w0i + 1;
        const bool h0k = (unsigned)h0 < 64u, h1k = (unsigned)h1 < 64u;
        const bool w0k = (unsigned)w0i < 64u, w1k = (unsigned)w1i < 64u;
        const int tb = tcb * HW_;
        const int h0c = (h0 < 0 ? 0 : (h0 > 63 ? 63 : h0)) * W_;
        const int h1c = (h1 < 0 ? 0 : (h1 > 63 ? 63 : h1)) * W_;
        const int w0c = w0i < 0 ? 0 : (w0i > 63 ? 63 : w0i);
        const int w1c = w1i < 0 ? 0 : (w1i > 63 ? 63 : w1i);
        const float f0 = (tok && h0k && w0k) ? (1.f - fh) * (1.f - fw) : 0.f;
        const float f1 = (tok && h0k && w1k) ? (1.f - fh) * fw : 0.f;
        const float f2 = (tok && h1k && w0k) ? fh * (1.f - fw) : 0.f;
        const float f3 = (tok && h1k && w1k) ? fh * fw : 0.f;
        const int cb = c4 * 4;
        const float4 A = *reinterpret_cast<const float4*>(xT + (tb + h0c + w0c) * 64 + cb);
        const float4 B = *reinterpret_cast<const float4*>(xT + (tb + h0c + w1c) * 64 + cb);
        const float4 C = *reinterpret_cast<const float4*>(xT + (tb + h1c + w0c) * 64 + cb);
        const float4 D = *reinterpret_cast<const float4*>(xT + (tb + h1c + w1c) * 64 + cb);
        float s0 = fmaf(f0, A.x, fmaf(f1, B.x, fmaf(f2, C.x, f3 * D.x)));
        float s1 = fmaf(f0, A.y, fmaf(f1, B.y, fmaf(f2, C.y, f3 * D.y)));
        float s2 = fmaf(f0, A.z, fmaf(f1, B.z, fmaf(f2, C.z, f3 * D.z)));
        float s3 = fmaf(f0, A.w, fmaf(f1, B.w, fmaf(f2, C.w, f3 * D.w)));
        ushort4 hv, lv;
        split_tr(s0, hv.x, lv.x); split_tr(s1, hv.y, lv.y);
        split_tr(s2, hv.z, lv.z); split_tr(s3, hv.w, lv.w);
        const int ci = (cb) ^ ((wp & 7) << 3);
        *reinterpret_cast<ushort4*>(&A_l[0][wp][ci]) = hv;
        *reinterpret_cast<ushort4*>(&A_l[1][wp][ci]) = lv;
        const unsigned short* wt = wB + k * 8192 + bo * 64 + bc8 * 8;
        *reinterpret_cast<frag_ab*>(&B_l[0][bo][bi]) =
            *reinterpret_cast<const frag_ab*>(wt);
        *reinterpret_cast<frag_ab*>(&B_l[1][bo][bi]) =
            *reinterpret_cast<const frag_ab*>(wt + 4096);
        __syncthreads();
#pragma unroll
        for (int ks = 0; ks < 2; ++ks) {
            const int ka = ks * 32 + kg * 8;
            const frag_ab ah = *reinterpret_cast<const frag_ab*>(&A_l[0][arow][ka ^ ((arow & 7) << 3)]);
            const frag_ab al = *reinterpret_cast<const frag_ab*>(&A_l[1][arow][ka ^ ((arow & 7) << 3)]);
            const frag_ab bh = *reinterpret_cast<const frag_ab*>(&B_l[0][brow][ka ^ ((brow & 7) << 3)]);
            const frag_ab bl = *reinterpret_cast<const frag_ab*>(&B_l[1][brow][ka ^ ((brow & 7) << 3)]);
            acc = __builtin_amdgcn_mfma_f32_16x16x32_bf16(ah, bh, acc, 0, 0, 0);
            acc = __builtin_amdgcn_mfma_f32_16x16x32_bf16(ah, bl, acc, 0, 0, 0);
            acc = __builtin_amdgcn_mfma_f32_16x16x32_bf16(al, bh, acc, 0, 0, 0);
        }
        __syncthreads();
    }

    const int o = otile * 16 + ln15;
    if (MODE == 0) {
        // leaky-relu -> NHWC yT
#pragma unroll
        for (int reg = 0; reg < 4; ++reg) {
            const int wl_ = wtile * 16 + kg * 4 + reg;
            float v = acc[reg];
            v = v > 0.f ? v : 0.1f * v;
            out[(posb + wl_) * 64 + o] = v;
        }
    } else {
        // transpose via LDS, then coalesced NCTHW + residual
#pragma unroll
        for (int reg = 0; reg < 4; ++reg) {
            const int wl_ = wtile * 16 + kg * 4 + reg;
            ep[wl_][o] = acc[reg];
        }
        __syncthreads();
        const int w2 = tid & 31, og = tid >> 5;  // og 0..15
#pragma unroll
        for (int i = 0; i < 4; ++i) {
            const int oc = og + i * 16;
            out[oc * THW_ + posb + w2] = ep[w2][oc] + resid[oc * THW_ + posb + w2];
        }
    }
}

// ---------------------------------------------------------------------------
extern "C" void kernel_launch(void* const* d_in, const int* in_sizes, int n_in,
                              void* d_out, int out_size, void* d_ws, size_t ws_size,
                              hipStream_t stream) {
    (void)in_sizes; (void)n_in; (void)out_size; (void)ws_size;
    const float* x      = (const float*)d_in[0];
    const float* w_off0 = (const float*)d_in[1];
    const float* b_off0 = (const float*)d_in[2];
    const float* w0     = (const float*)d_in[3];
    const float* w_off1 = (const float*)d_in[4];
    const float* b_off1 = (const float*)d_in[5];
    const float* w1     = (const float*)d_in[6];
    float* out = (float*)d_out;

    float* ws = (float*)d_ws;
    float* xT   = ws;                          // 64*THW
    float* yT   = xT + 64 * THW_;              // 64*THW
    float* offT = yT + 64 * THW_;              // THW*56
    unsigned short* wc0 = (unsigned short*)(offT + THW_ * OFFSTR);  // 27*2*64*64 each
    unsigned short* wc1 = wc0 + 221184;
    unsigned short* wd0 = wc1 + 221184;
    unsigned short* wd1 = wd0 + 221184;

    prep_wt_kernel<<<1728, 256, 0, stream>>>(w_off0, w_off1, w0, w1,
                                             wc0, wc1, wd0, wd1);
    transpose_kernel<<<448, 256, 0, stream>>>(x, xT);
    conv_off_kernel<<<896, 512, 0, stream>>>(xT, wc0, b_off0, offT);
    dcn_kernel<0><<<896, 512, 0, stream>>>(xT, offT, wd0, nullptr, yT);
    conv_off_kernel<<<896, 512, 0, stream>>>(yT, wc1, b_off1, offT);
    dcn_kernel<1><<<896, 512, 0, stream>>>(yT, offT, wd1, x, out);
}

// Round 14
// 260.687 us; speedup vs baseline: 2.4604x; 1.0180x over previous
//
#include <hip/hip_runtime.h>

#define T_ 7
#define H_ 64
#define W_ 64
#define KK_ 27
#define HW_ 4096
#define THW_ 28672
#define CO_OFF 54
#define OFFSTR 56   // offT row stride (floats), 8B-aligned

using frag_ab = __attribute__((ext_vector_type(8))) short;  // 8 bf16
using f32x4   = __attribute__((ext_vector_type(4))) float;  // 4 fp32 acc

__device__ __forceinline__ unsigned short f2bf(float v) {
    unsigned u = __float_as_uint(v);
    unsigned r = u + 0x7FFFu + ((u >> 16) & 1u);
    return (unsigned short)(r >> 16);
}
__device__ __forceinline__ float bf2f(unsigned short h) {
    return __uint_as_float(((unsigned)h) << 16);
}
// rounded split (weight prep only)
__device__ __forceinline__ void split_bf(float v, unsigned short& hi, unsigned short& lo) {
    hi = f2bf(v);
    lo = f2bf(v - bf2f(hi));
}
// truncation split (hot path): 4 VALU ops/value, ~2^-14 scheme error.
__device__ __forceinline__ void split_tr(float v, unsigned short& hi, unsigned short& lo) {
    unsigned u = __float_as_uint(v);
    hi = (unsigned short)(u >> 16);
    float r = v - __uint_as_float(u & 0xFFFF0000u);
    lo = (unsigned short)(__float_as_uint(r) >> 16);
}

// ---------------------------------------------------------------------------
// Weight prep: split into bf16 hi/lo planes, [tap][plane][o][c], o padded.
// ---------------------------------------------------------------------------
__global__ void prep_wt_kernel(const float* __restrict__ w_off0,
                               const float* __restrict__ w_off1,
                               const float* __restrict__ w0,
                               const float* __restrict__ w1,
                               unsigned short* __restrict__ wc0,
                               unsigned short* __restrict__ wc1,
                               unsigned short* __restrict__ wd0,
                               unsigned short* __restrict__ wd1) {
    int idx = blockIdx.x * 256 + threadIdx.x;   // 4 * 110592
    int which = idx / 110592;
    int r = idx - which * 110592;
    int tap = r >> 12;
    int o = (r >> 6) & 63;
    int c = r & 63;
    const float* src;
    unsigned short* dst;
    int Co;
    switch (which) {
        case 0:  src = w_off0; dst = wc0; Co = CO_OFF; break;
        case 1:  src = w_off1; dst = wc1; Co = CO_OFF; break;
        case 2:  src = w0;     dst = wd0; Co = 64;     break;
        default: src = w1;     dst = wd1; Co = 64;     break;
    }
    float v = 0.f;
    if (o < Co) v = src[o * 1728 + c * 27 + tap];
    unsigned short hi, lo;
    split_bf(v, hi, lo);
    dst[tap * 8192 + 0 * 4096 + o * 64 + c] = hi;
    dst[tap * 8192 + 1 * 4096 + o * 64 + c] = lo;
}

// ---------------------------------------------------------------------------
// NCTHW -> NHWC transpose: xT[pos*64 + c] = x[c*THW + pos]
// ---------------------------------------------------------------------------
__global__ void __launch_bounds__(256) transpose_kernel(
    const float* __restrict__ x, float* __restrict__ xT) {
    __shared__ float lx[64][65];
    const int tid = threadIdx.x;
    const int base = blockIdx.x * 64;
    const int w = tid & 63, cg = tid >> 6;
#pragma unroll
    for (int i = 0; i < 16; ++i) {
        const int c = cg * 16 + i;
        lx[c][w] = x[c * THW_ + base + w];
    }
    __syncthreads();
    const int c = tid & 63, j0 = tid >> 6;
#pragma unroll
    for (int j = 0; j < 16; ++j) {
        const int wp = j * 4 + j0;
        xT[(base + wp) * 64 + c] = lx[c][wp];
    }
}

// ---------------------------------------------------------------------------
// T14 async-STAGE structure (both GEMM kernels): per tap k, ISSUE tap k+1's
// global loads into registers BEFORE tap k's MFMA; after the post-MFMA
// barrier, combine/split and write LDS; barrier. Load latency hides under
// the MFMA phase. Single LDS buffer (occupancy preserved), 2 barriers/tap.
// ---------------------------------------------------------------------------

// Plain conv producing offsets -> NHWC offT[pos*56 + ch] (+bias, ch<54).
__global__ void __launch_bounds__(512, 8) conv_off_kernel(
    const float* __restrict__ xT, const unsigned short* __restrict__ wB,
    const float* __restrict__ bias, float* __restrict__ offT) {
    __shared__ __align__(16) unsigned short A_l[2][32][64];
    __shared__ __align__(16) unsigned short B_l[2][64][64];
    const int tid = threadIdx.x;
    const int bid = blockIdx.x;
    const int t = bid >> 7, h = (bid >> 1) & 63, wh = bid & 1;
    const int wg = wh * 32;
    const int c4 = tid & 15;
    const int wp = tid >> 4;
    const int lane = tid & 63, wid = tid >> 6;
    const int wtile = wid & 1, otile = wid >> 1;
    const int ln15 = lane & 15, kg = lane >> 4;
    const int arow = wtile * 16 + ln15;
    const int brow = otile * 16 + ln15;
    const int posb = t * HW_ + h * W_ + wg;
    const int bo = (tid >> 3) & 63, bc8 = tid & 7;
    const int bi = (bc8 * 8) ^ ((bo & 7) << 3);
    const int ci = (c4 * 4) ^ ((wp & 7) << 3);

    f32x4 acc = {0.f, 0.f, 0.f, 0.f};

    // ---- prologue: stage tap 0 ----
    {
        const int ts = t - 1, hs = h - 1, wsr = wg + wp - 1;
        const bool ok = ((unsigned)ts < 7u) & ((unsigned)hs < 64u) & ((unsigned)wsr < 64u);
        float4 v = make_float4(0.f, 0.f, 0.f, 0.f);
        if (ok)
            v = *reinterpret_cast<const float4*>(xT + (ts * HW_ + hs * W_ + wsr) * 64 + c4 * 4);
        ushort4 hv, lv;
        split_tr(v.x, hv.x, lv.x); split_tr(v.y, hv.y, lv.y);
        split_tr(v.z, hv.z, lv.z); split_tr(v.w, hv.w, lv.w);
        *reinterpret_cast<ushort4*>(&A_l[0][wp][ci]) = hv;
        *reinterpret_cast<ushort4*>(&A_l[1][wp][ci]) = lv;
        const unsigned short* wt = wB + bo * 64 + bc8 * 8;
        *reinterpret_cast<frag_ab*>(&B_l[0][bo][bi]) = *reinterpret_cast<const frag_ab*>(wt);
        *reinterpret_cast<frag_ab*>(&B_l[1][bo][bi]) = *reinterpret_cast<const frag_ab*>(wt + 4096);
    }
    __syncthreads();

    float4 vn;
    frag_ab b0n, b1n;
    for (int k = 0; k < KK_; ++k) {
        // ---- issue tap k+1 loads (hide under MFMA) ----
        if (k + 1 < KK_) {
            const int kk = k + 1;
            const int kt = kk / 9 - 1, kh = (kk / 3) % 3 - 1, kw = kk % 3 - 1;
            const int ts = t + kt, hs = h + kh, wsr = wg + wp + kw;
            const bool ok = ((unsigned)ts < 7u) & ((unsigned)hs < 64u) & ((unsigned)wsr < 64u);
            vn = make_float4(0.f, 0.f, 0.f, 0.f);
            if (ok)
                vn = *reinterpret_cast<const float4*>(xT + (ts * HW_ + hs * W_ + wsr) * 64 + c4 * 4);
            const unsigned short* wt = wB + kk * 8192 + bo * 64 + bc8 * 8;
            b0n = *reinterpret_cast<const frag_ab*>(wt);
            b1n = *reinterpret_cast<const frag_ab*>(wt + 4096);
        }
        // ---- MFMA on staged tap k ----
#pragma unroll
        for (int ks = 0; ks < 2; ++ks) {
            const int ka = ks * 32 + kg * 8;
            const frag_ab ah = *reinterpret_cast<const frag_ab*>(&A_l[0][arow][ka ^ ((arow & 7) << 3)]);
            const frag_ab al = *reinterpret_cast<const frag_ab*>(&A_l[1][arow][ka ^ ((arow & 7) << 3)]);
            const frag_ab bh = *reinterpret_cast<const frag_ab*>(&B_l[0][brow][ka ^ ((brow & 7) << 3)]);
            const frag_ab bl = *reinterpret_cast<const frag_ab*>(&B_l[1][brow][ka ^ ((brow & 7) << 3)]);
            acc = __builtin_amdgcn_mfma_f32_16x16x32_bf16(ah, bh, acc, 0, 0, 0);
            acc = __builtin_amdgcn_mfma_f32_16x16x32_bf16(ah, bl, acc, 0, 0, 0);
            acc = __builtin_amdgcn_mfma_f32_16x16x32_bf16(al, bh, acc, 0, 0, 0);
        }
        __syncthreads();
        // ---- write tap k+1 into LDS ----
        if (k + 1 < KK_) {
            ushort4 hv, lv;
            split_tr(vn.x, hv.x, lv.x); split_tr(vn.y, hv.y, lv.y);
            split_tr(vn.z, hv.z, lv.z); split_tr(vn.w, hv.w, lv.w);
            *reinterpret_cast<ushort4*>(&A_l[0][wp][ci]) = hv;
            *reinterpret_cast<ushort4*>(&A_l[1][wp][ci]) = lv;
            *reinterpret_cast<frag_ab*>(&B_l[0][bo][bi]) = b0n;
            *reinterpret_cast<frag_ab*>(&B_l[1][bo][bi]) = b1n;
        }
        __syncthreads();
    }

    const int o = otile * 16 + ln15;
    if (o < CO_OFF) {
        const float b = bias[o];
#pragma unroll
        for (int reg = 0; reg < 4; ++reg) {
            const int wl_ = wtile * 16 + kg * 4 + reg;
            offT[(posb + wl_) * OFFSTR + o] = acc[reg] + b;
        }
    }
}

// Deformable conv. MODE 0: leaky_relu -> NHWC yT. MODE 1: +resid -> NCTHW out.
template <int MODE>
__global__ void __launch_bounds__(512, 8) dcn_kernel(
    const float* __restrict__ xT, const float* __restrict__ offT,
    const unsigned short* __restrict__ wB, const float* __restrict__ resid,
    float* __restrict__ out) {
    __shared__ __align__(16) unsigned short A_l[2][32][64];
    __shared__ __align__(16) unsigned short B_l[2][64][64];
    __shared__ float ep[32][65];
    const int tid = threadIdx.x;
    const int bid = blockIdx.x;
    const int t = bid >> 7, h = (bid >> 1) & 63, wh = bid & 1;
    const int wg = wh * 32;
    const int c4 = tid & 15;
    const int wp = tid >> 4;
    const int lane = tid & 63, wid = tid >> 6;
    const int wtile = wid & 1, otile = wid >> 1;
    const int ln15 = lane & 15, kg = lane >> 4;
    const int arow = wtile * 16 + ln15;
    const int brow = otile * 16 + ln15;
    const int posb = t * HW_ + h * W_ + wg;
    const int bo = (tid >> 3) & 63, bc8 = tid & 7;
    const int bi = (bc8 * 8) ^ ((bo & 7) << 3);
    const int ci = (c4 * 4) ^ ((wp & 7) << 3);
    const int cb = c4 * 4;

    f32x4 acc = {0.f, 0.f, 0.f, 0.f};
    const int w = wg + wp;
    const float* offp = offT + (posb + wp) * OFFSTR;

    // corner computation for tap kk given its offsets (of2)
    auto corners = [&](int kk, float2 of2, int& i0, int& i1, int& i2, int& i3,
                       float& f0, float& f1, float& f2, float& f3) {
        const int kt = kk / 9 - 1, kh = (kk / 3) % 3 - 1, kw = kk % 3 - 1;
        const int ts = t + kt;
        const bool tok = (unsigned)ts < 7u;
        const int tcb = ts < 0 ? 0 : (ts > 6 ? 6 : ts);
        const float ph = (float)(h + kh) + of2.x;
        const float pw = (float)(w + kw) + of2.y;
        const float h0f = floorf(ph), w0f = floorf(pw);
        const float fh = ph - h0f, fw = pw - w0f;
        const int h0 = (int)h0f, w0i = (int)w0f;
        const int h1 = h0 + 1, w1i = w0i + 1;
        const bool h0k = (unsigned)h0 < 64u, h1k = (unsigned)h1 < 64u;
        const bool w0k = (unsigned)w0i < 64u, w1k = (unsigned)w1i < 64u;
        const int tb = tcb * HW_;
        const int h0c = (h0 < 0 ? 0 : (h0 > 63 ? 63 : h0)) * W_;
        const int h1c = (h1 < 0 ? 0 : (h1 > 63 ? 63 : h1)) * W_;
        const int w0c = w0i < 0 ? 0 : (w0i > 63 ? 63 : w0i);
        const int w1c = w1i < 0 ? 0 : (w1i > 63 ? 63 : w1i);
        i0 = tb + h0c + w0c; i1 = tb + h0c + w1c;
        i2 = tb + h1c + w0c; i3 = tb + h1c + w1c;
        f0 = (tok && h0k && w0k) ? (1.f - fh) * (1.f - fw) : 0.f;
        f1 = (tok && h0k && w1k) ? (1.f - fh) * fw : 0.f;
        f2 = (tok && h1k && w0k) ? fh * (1.f - fw) : 0.f;
        f3 = (tok && h1k && w1k) ? fh * fw : 0.f;
    };

    // ---- prologue: stage tap 0; prefetch tap-1 offsets ----
    float2 ofN;  // offsets for tap k+1 (2-deep prefetch)
    {
        const float2 of0 = *reinterpret_cast<const float2*>(offp);
        ofN = *reinterpret_cast<const float2*>(offp + 2);
        int i0, i1, i2, i3; float f0, f1, f2, f3;
        corners(0, of0, i0, i1, i2, i3, f0, f1, f2, f3);
        const float4 A = *reinterpret_cast<const float4*>(xT + i0 * 64 + cb);
        const float4 B = *reinterpret_cast<const float4*>(xT + i1 * 64 + cb);
        const float4 C = *reinterpret_cast<const float4*>(xT + i2 * 64 + cb);
        const float4 D = *reinterpret_cast<const float4*>(xT + i3 * 64 + cb);
        float s0 = fmaf(f0, A.x, fmaf(f1, B.x, fmaf(f2, C.x, f3 * D.x)));
        float s1 = fmaf(f0, A.y, fmaf(f1, B.y, fmaf(f2, C.y, f3 * D.y)));
        float s2 = fmaf(f0, A.z, fmaf(f1, B.z, fmaf(f2, C.z, f3 * D.z)));
        float s3 = fmaf(f0, A.w, fmaf(f1, B.w, fmaf(f2, C.w, f3 * D.w)));
        ushort4 hv, lv;
        split_tr(s0, hv.x, lv.x); split_tr(s1, hv.y, lv.y);
        split_tr(s2, hv.z, lv.z); split_tr(s3, hv.w, lv.w);
        *reinterpret_cast<ushort4*>(&A_l[0][wp][ci]) = hv;
        *reinterpret_cast<ushort4*>(&A_l[1][wp][ci]) = lv;
        const unsigned short* wt = wB + bo * 64 + bc8 * 8;
        *reinterpret_cast<frag_ab*>(&B_l[0][bo][bi]) = *reinterpret_cast<const frag_ab*>(wt);
        *reinterpret_cast<frag_ab*>(&B_l[1][bo][bi]) = *reinterpret_cast<const frag_ab*>(wt + 4096);
    }
    __syncthreads();

    float4 An, Bn, Cn, Dn;
    float f0n, f1n, f2n, f3n;
    frag_ab b0n, b1n;
    for (int k = 0; k < KK_; ++k) {
        // ---- issue tap k+1 loads (corners from prefetched offsets) ----
        if (k + 1 < KK_) {
            int i0, i1, i2, i3;
            corners(k + 1, ofN, i0, i1, i2, i3, f0n, f1n, f2n, f3n);
            An = *reinterpret_cast<const float4*>(xT + i0 * 64 + cb);
            Bn = *reinterpret_cast<const float4*>(xT + i1 * 64 + cb);
            Cn = *reinterpret_cast<const float4*>(xT + i2 * 64 + cb);
            Dn = *reinterpret_cast<const float4*>(xT + i3 * 64 + cb);
            const unsigned short* wt = wB + (k + 1) * 8192 + bo * 64 + bc8 * 8;
            b0n = *reinterpret_cast<const frag_ab*>(wt);
            b1n = *reinterpret_cast<const frag_ab*>(wt + 4096);
            if (k + 2 < KK_)
                ofN = *reinterpret_cast<const float2*>(offp + 2 * (k + 2));
        }
        // ---- MFMA on staged tap k ----
#pragma unroll
        for (int ks = 0; ks < 2; ++ks) {
            const int ka = ks * 32 + kg * 8;
            const frag_ab ah = *reinterpret_cast<const frag_ab*>(&A_l[0][arow][ka ^ ((arow & 7) << 3)]);
            const frag_ab al = *reinterpret_cast<const frag_ab*>(&A_l[1][arow][ka ^ ((arow & 7) << 3)]);
            const frag_ab bh = *reinterpret_cast<const frag_ab*>(&B_l[0][brow][ka ^ ((brow & 7) << 3)]);
            const frag_ab bl = *reinterpret_cast<const frag_ab*>(&B_l[1][brow][ka ^ ((brow & 7) << 3)]);
            acc = __builtin_amdgcn_mfma_f32_16x16x32_bf16(ah, bh, acc, 0, 0, 0);
            acc = __builtin_amdgcn_mfma_f32_16x16x32_bf16(ah, bl, acc, 0, 0, 0);
            acc = __builtin_amdgcn_mfma_f32_16x16x32_bf16(al, bh, acc, 0, 0, 0);
        }
        __syncthreads();
        // ---- combine + write tap k+1 into LDS ----
        if (k + 1 < KK_) {
            float s0 = fmaf(f0n, An.x, fmaf(f1n, Bn.x, fmaf(f2n, Cn.x, f3n * Dn.x)));
            float s1 = fmaf(f0n, An.y, fmaf(f1n, Bn.y, fmaf(f2n, Cn.y, f3n * Dn.y)));
            float s2 = fmaf(f0n, An.z, fmaf(f1n, Bn.z, fmaf(f2n, Cn.z, f3n * Dn.z)));
            float s3 = fmaf(f0n, An.w, fmaf(f1n, Bn.w, fmaf(f2n, Cn.w, f3n * Dn.w)));
            ushort4 hv, lv;
            split_tr(s0, hv.x, lv.x); split_tr(s1, hv.y, lv.y);
            split_tr(s2, hv.z, lv.z); split_tr(s3, hv.w, lv.w);
            *reinterpret_cast<ushort4*>(&A_l[0][wp][ci]) = hv;
            *reinterpret_cast<ushort4*>(&A_l[1][wp][ci]) = lv;
            *reinterpret_cast<frag_ab*>(&B_l[0][bo][bi]) = b0n;
            *reinterpret_cast<frag_ab*>(&B_l[1][bo][bi]) = b1n;
        }
        __syncthreads();
    }

    const int o = otile * 16 + ln15;
    if (MODE == 0) {
#pragma unroll
        for (int reg = 0; reg < 4; ++reg) {
            const int wl_ = wtile * 16 + kg * 4 + reg;
            float v = acc[reg];
            v = v > 0.f ? v : 0.1f * v;
            out[(posb + wl_) * 64 + o] = v;
        }
    } else {
#pragma unroll
        for (int reg = 0; reg < 4; ++reg) {
            const int wl_ = wtile * 16 + kg * 4 + reg;
            ep[wl_][o] = acc[reg];
        }
        __syncthreads();
        const int w2 = tid & 31, og = tid >> 5;
#pragma unroll
        for (int i = 0; i < 4; ++i) {
            const int oc = og + i * 16;
            out[oc * THW_ + posb + w2] = ep[w2][oc] + resid[oc * THW_ + posb + w2];
        }
    }
}

// ---------------------------------------------------------------------------
extern "C" void kernel_launch(void* const* d_in, const int* in_sizes, int n_in,
                              void* d_out, int out_size, void* d_ws, size_t ws_size,
                              hipStream_t stream) {
    (void)in_sizes; (void)n_in; (void)out_size; (void)ws_size;
    const float* x      = (const float*)d_in[0];
    const float* w_off0 = (const float*)d_in[1];
    const float* b_off0 = (const float*)d_in[2];
    const float* w0     = (const float*)d_in[3];
    const float* w_off1 = (const float*)d_in[4];
    const float* b_off1 = (const float*)d_in[5];
    const float* w1     = (const float*)d_in[6];
    float* out = (float*)d_out;

    float* ws = (float*)d_ws;
    float* xT   = ws;                          // 64*THW
    float* yT   = xT + 64 * THW_;              // 64*THW
    float* offT = yT + 64 * THW_;              // THW*56
    unsigned short* wc0 = (unsigned short*)(offT + THW_ * OFFSTR);  // 27*2*64*64 each
    unsigned short* wc1 = wc0 + 221184;
    unsigned short* wd0 = wc1 + 221184;
    unsigned short* wd1 = wd0 + 221184;

    prep_wt_kernel<<<1728, 256, 0, stream>>>(w_off0, w_off1, w0, w1,
                                             wc0, wc1, wd0, wd1);
    transpose_kernel<<<448, 256, 0, stream>>>(x, xT);
    conv_off_kernel<<<896, 512, 0, stream>>>(xT, wc0, b_off0, offT);
    dcn_kernel<0><<<896, 512, 0, stream>>>(xT, offT, wd0, nullptr, yT);
    conv_off_kernel<<<896, 512, 0, stream>>>(yT, wc1, b_off1, offT);
    dcn_kernel<1><<<896, 512, 0, stream>>>(yT, offT, wd1, x, out);
}